// Round 5
// baseline (1237.744 us; speedup 1.0000x reference)
//
#include <hip/hip_runtime.h>
#include <hip/hip_bf16.h>

typedef __hip_bfloat16 bf16;

#define NN 16384          // gate nodes
#define BBG 64            // graphs
#define EE 49152          // directed edges (no self loops)
#define ET (EE + NN)      // edges + self loops = 65536
#define DD 512            // node feature dim (2F)
#define NG (NN / BBG)     // 256 nodes per graph

__device__ __forceinline__ float b2f(bf16 v) { return __bfloat162float(v); }
__device__ __forceinline__ bf16 f2b(float v) { return __float2bfloat16(v); }
__device__ __forceinline__ float sb2f(short s) {
    unsigned u = ((unsigned)(unsigned short)s) << 16;
    return __builtin_bit_cast(float, u);
}
__device__ __forceinline__ short f2bs(float v) {
    bf16 b = f2b(v);
    return __builtin_bit_cast(short, b);
}
__device__ __forceinline__ int clampi(int v, int lo, int hi)
{
    return v < lo ? lo : (v > hi ? hi : v);
}

typedef __attribute__((ext_vector_type(8))) short bf16x8;  // 8 bf16 = 4 VGPRs
typedef __attribute__((ext_vector_type(4))) float f32x4;

#define AS1 __attribute__((address_space(1)))
#define AS3 __attribute__((address_space(3)))

// ---------------------------------------------------------------------------
// MFMA bf16 GEMM (m97 structure): C[M,N] = act(A[M,K] @ Bt[N,K]^T + bias).
// R4 post-mortem: the R3 XCD swizzle REGRESSED these (~+200us non-gat time);
// reverted to the plain mapping.
// ---------------------------------------------------------------------------
__global__ __launch_bounds__(256) void gemm_mfma_bt(
    const bf16* __restrict__ A, const bf16* __restrict__ Bt,
    const float* __restrict__ bias, float* __restrict__ C,
    bf16* __restrict__ Cb, int M, int N, int K, float slope, int has_act)
{
    __shared__ bf16 As[128 * 32];
    __shared__ bf16 Bs[128 * 32];
    const int tid = threadIdx.x;
    const int w = tid >> 6;
    const int l = tid & 63;
    const int bm = blockIdx.y * 128;
    const int bn = blockIdx.x * 128;
    const int wrow = (w >> 1) * 64;
    const int wcol = (w & 1) * 64;
    const int quad = l >> 4;
    const int c16 = l & 15;

    const int lrow = l >> 2;
    const int lchunk = l & 3;
    const bf16* Ag = A + (size_t)(bm + w * 16 + lrow) * K + lchunk * 8;
    const bf16* Bg = Bt + (size_t)(bn + w * 16 + lrow) * K + lchunk * 8;
    char* AsB = (char*)As;
    char* BsB = (char*)Bs;

    f32x4 acc[4][4] = {};

    for (int k0 = 0; k0 < K; k0 += 32) {
        __builtin_amdgcn_global_load_lds((const AS1 void*)(Ag + k0),
            (AS3 void*)(AsB + w * 1024), 16, 0, 0);
        __builtin_amdgcn_global_load_lds((const AS1 void*)(Ag + (size_t)64 * K + k0),
            (AS3 void*)(AsB + 4096 + w * 1024), 16, 0, 0);
        __builtin_amdgcn_global_load_lds((const AS1 void*)(Bg + k0),
            (AS3 void*)(BsB + w * 1024), 16, 0, 0);
        __builtin_amdgcn_global_load_lds((const AS1 void*)(Bg + (size_t)64 * K + k0),
            (AS3 void*)(BsB + 4096 + w * 1024), 16, 0, 0);
        __syncthreads();

        bf16x8 a[4], b[4];
#pragma unroll
        for (int i = 0; i < 4; i++) {
            int ra = wrow + i * 16 + c16;
            a[i] = *(const bf16x8*)(AsB + ra * 64 + quad * 16);
            int rb = wcol + i * 16 + c16;
            b[i] = *(const bf16x8*)(BsB + rb * 64 + quad * 16);
        }
#pragma unroll
        for (int i = 0; i < 4; i++)
#pragma unroll
            for (int j = 0; j < 4; j++)
                acc[i][j] = __builtin_amdgcn_mfma_f32_16x16x32_bf16(
                    a[i], b[j], acc[i][j], 0, 0, 0);
        __syncthreads();
    }

#pragma unroll
    for (int i = 0; i < 4; i++) {
#pragma unroll
        for (int j = 0; j < 4; j++) {
            int col = bn + wcol + j * 16 + c16;
            float bv = bias ? bias[col] : 0.f;
#pragma unroll
            for (int r = 0; r < 4; r++) {
                int row = bm + wrow + i * 16 + quad * 4 + r;
                float v = acc[i][j][r] + bv;
                if (has_act) v = (v >= 0.f) ? v : v * slope;
                if (C)  C[(size_t)row * N + col] = v;
                if (Cb) Cb[(size_t)row * N + col] = f2b(v);
            }
        }
    }
}

// ---------------------------------------------------------------------------
// Merged dual GEMM: Bt = [wlT; wrT] (Ntot=2*HC rows). cols [0,HC) -> X0 (xl),
// cols [HC,2HC) -> X1 (xr).
// ---------------------------------------------------------------------------
__global__ __launch_bounds__(256) void gemm_mfma_dual(
    const bf16* __restrict__ A, const bf16* __restrict__ Bt,
    bf16* __restrict__ X0, bf16* __restrict__ X1,
    int M, int Ntot, int K, int HC)
{
    __shared__ bf16 As[128 * 32];
    __shared__ bf16 Bs[128 * 32];
    const int tid = threadIdx.x;
    const int w = tid >> 6;
    const int l = tid & 63;
    const int bm = blockIdx.y * 128;
    const int bn = blockIdx.x * 128;
    const int wrow = (w >> 1) * 64;
    const int wcol = (w & 1) * 64;
    const int quad = l >> 4;
    const int c16 = l & 15;

    const int lrow = l >> 2;
    const int lchunk = l & 3;
    const bf16* Ag = A + (size_t)(bm + w * 16 + lrow) * K + lchunk * 8;
    const bf16* Bg = Bt + (size_t)(bn + w * 16 + lrow) * K + lchunk * 8;
    char* AsB = (char*)As;
    char* BsB = (char*)Bs;

    f32x4 acc[4][4] = {};

    for (int k0 = 0; k0 < K; k0 += 32) {
        __builtin_amdgcn_global_load_lds((const AS1 void*)(Ag + k0),
            (AS3 void*)(AsB + w * 1024), 16, 0, 0);
        __builtin_amdgcn_global_load_lds((const AS1 void*)(Ag + (size_t)64 * K + k0),
            (AS3 void*)(AsB + 4096 + w * 1024), 16, 0, 0);
        __builtin_amdgcn_global_load_lds((const AS1 void*)(Bg + k0),
            (AS3 void*)(BsB + w * 1024), 16, 0, 0);
        __builtin_amdgcn_global_load_lds((const AS1 void*)(Bg + (size_t)64 * K + k0),
            (AS3 void*)(BsB + 4096 + w * 1024), 16, 0, 0);
        __syncthreads();

        bf16x8 a[4], b[4];
#pragma unroll
        for (int i = 0; i < 4; i++) {
            int ra = wrow + i * 16 + c16;
            a[i] = *(const bf16x8*)(AsB + ra * 64 + quad * 16);
            int rb = wcol + i * 16 + c16;
            b[i] = *(const bf16x8*)(BsB + rb * 64 + quad * 16);
        }
#pragma unroll
        for (int i = 0; i < 4; i++)
#pragma unroll
            for (int j = 0; j < 4; j++)
                acc[i][j] = __builtin_amdgcn_mfma_f32_16x16x32_bf16(
                    a[i], b[j], acc[i][j], 0, 0, 0);
        __syncthreads();
    }

#pragma unroll
    for (int i = 0; i < 4; i++) {
#pragma unroll
        for (int j = 0; j < 4; j++) {
            int col = bn + wcol + j * 16 + c16;
            bf16* dst = (col < HC) ? (X0 + col) : (X1 + col - HC);
#pragma unroll
            for (int r = 0; r < 4; r++) {
                int row = bm + wrow + i * 16 + quad * 4 + r;
                dst[(size_t)row * HC] = f2b(acc[i][j][r]);
            }
        }
    }
}

// ---------------------------------------------------------------------------
// fp32 GEMM (head MLP only)
// ---------------------------------------------------------------------------
__global__ __launch_bounds__(256) void gemm_f32(
    const float* __restrict__ A, const float* __restrict__ W,
    const float* __restrict__ bias, float* __restrict__ C,
    int M, int N, int K, float slope, int has_act)
{
    const int BK = 16;
    __shared__ float Asm[BK][64 + 1];
    __shared__ float Wsm[BK][64 + 1];
    int tid = threadIdx.x;
    int bm = blockIdx.y * 64;
    int bn = blockIdx.x * 64;
    int tr = tid >> 4;
    int tc = tid & 15;
    float acc[4][4] = {};

    for (int k0 = 0; k0 < K; k0 += BK) {
        {
            int col = tid & 15;
            int row = tid >> 4;
#pragma unroll
            for (int p = 0; p < 4; p++) {
                int r = row + p * 16;
                Asm[col][r] = A[(size_t)(bm + r) * K + k0 + col];
            }
        }
        {
            int wc = tid & 63;
            int wr = tid >> 6;
#pragma unroll
            for (int p = 0; p < 4; p++) {
                int r = wr + p * 4;
                Wsm[r][wc] = W[(size_t)(k0 + r) * N + bn + wc];
            }
        }
        __syncthreads();
#pragma unroll
        for (int kk = 0; kk < BK; kk++) {
            float a[4], w[4];
#pragma unroll
            for (int i = 0; i < 4; i++) a[i] = Asm[kk][tr * 4 + i];
#pragma unroll
            for (int j = 0; j < 4; j++) w[j] = Wsm[kk][tc * 4 + j];
#pragma unroll
            for (int i = 0; i < 4; i++)
#pragma unroll
                for (int j = 0; j < 4; j++)
                    acc[i][j] += a[i] * w[j];
        }
        __syncthreads();
    }
#pragma unroll
    for (int i = 0; i < 4; i++) {
        int r = bm + tr * 4 + i;
#pragma unroll
        for (int j = 0; j < 4; j++) {
            int cn = bn + tc * 4 + j;
            float v = acc[i][j];
            if (bias) v += bias[cn];
            if (has_act) v = (v >= 0.f) ? v : v * slope;
            C[(size_t)r * N + cn] = v;
        }
    }
}

// ---------------------------------------------------------------------------
// Batched fp32 [R,C] -> bf16 [C,R] transpose-convert (z selects tensor pair)
// ---------------------------------------------------------------------------
__global__ __launch_bounds__(256) void transpose_f2b2(
    const float* __restrict__ in0, bf16* __restrict__ out0,
    const float* __restrict__ in1, bf16* __restrict__ out1, int R, int C)
{
    const float* in = blockIdx.z ? in1 : in0;
    bf16* out = blockIdx.z ? out1 : out0;
    __shared__ float tile[32][33];
    int c0 = blockIdx.x * 32;
    int r0 = blockIdx.y * 32;
    int tx = threadIdx.x & 31;
    int ty = threadIdx.x >> 5;
#pragma unroll
    for (int k = 0; k < 4; k++) {
        int r = ty + k * 8;
        tile[r][tx] = in[(size_t)(r0 + r) * C + c0 + tx];
    }
    __syncthreads();
#pragma unroll
    for (int k = 0; k < 4; k++) {
        int rr = ty + k * 8;
        out[(size_t)(c0 + rr) * R + r0 + tx] = f2b(tile[tx][rr]);
    }
}

__global__ void f2b_vec(const float* __restrict__ in, bf16* __restrict__ out, int n)
{
    int i = blockIdx.x * 256 + threadIdx.x;
    if (i < n) out[i] = f2b(in[i]);
}

// ---------------------------------------------------------------------------
// CSR build over dst (self loops: edge ids [EE, ET) are node e-EE)
// ---------------------------------------------------------------------------
__global__ void count_deg(const int* __restrict__ ei, int* __restrict__ deg)
{
    int e = blockIdx.x * 256 + threadIdx.x;
    if (e >= ET) return;
    int d = (e < EE) ? ei[EE + e] : (e - EE);
    d = clampi(d, 0, NN - 1);
    atomicAdd(&deg[d], 1);
}

__global__ __launch_bounds__(256) void scan_deg(const int* __restrict__ deg,
                                                int* __restrict__ rs)
{
    __shared__ int part[256];
    __shared__ int psum[257];
    int tid = threadIdx.x;
    const int per = NN / 256;
    int base = tid * per;
    int s = 0;
    for (int i = 0; i < per; i++) s += deg[base + i];
    part[tid] = s;
    __syncthreads();
    if (tid == 0) {
        int acc = 0;
        for (int i = 0; i < 256; i++) { psum[i] = acc; acc += part[i]; }
        psum[256] = acc;
    }
    __syncthreads();
    int acc = psum[tid];
    for (int i = 0; i < per; i++) { rs[base + i] = acc; acc += deg[base + i]; }
    if (tid == 0) rs[NN] = psum[256];
}

__global__ void fill_csr(const int* __restrict__ ei, const int* __restrict__ rs,
                         int* __restrict__ cur, int* __restrict__ csrc)
{
    int e = blockIdx.x * 256 + threadIdx.x;
    if (e >= ET) return;
    int s, d;
    if (e < EE) { s = ei[e]; d = ei[EE + e]; } else { s = d = e - EE; }
    s = clampi(s, 0, NN - 1);
    d = clampi(d, 0, NN - 1);
    int pos = atomicAdd(&cur[d], 1);
    int slot = clampi(rs[d] + pos, 0, ET - 1);
    csrc[slot] = s;
}

// ---------------------------------------------------------------------------
// GAT v9 (HC=1024 layers): 3-pass XCD-channel-resident formulation.
// R2-R4 showed the random full-row gather is pinned at ~1.5 TB/s of L2-miss
// traffic regardless of schedule (per-XCD L2 4MB << xl 32MB -> ~87% miss).
// Fix: pin each XCD to a 128-channel slice (16384 x 128 x 2B = 4MB = L2) via
// slice = blockIdx & 7 (hw dispatches consecutive blocks round-robin across
// XCDs). Gathers then hit L2. The full-row logit dot is split into per-slice
// partial dots (pass 1), reduced + softmaxed per dst (pass 2, tiny), and the
// weighted sum runs per-slice again (pass 3, fused bias+LeakyReLU+1/den).
// ---------------------------------------------------------------------------

// pass 1: pl[slice][edge] = partial logit over 128 channels.
// grid 2048 = 256 chunks x 8 slices; block = 4 waves; wave = 16 dsts.
__global__ __launch_bounds__(256) void gat_logit1024(
    const bf16* __restrict__ xl, const bf16* __restrict__ xr,
    const float* __restrict__ att,
    const int* __restrict__ rs, const int* __restrict__ csrc,
    float* __restrict__ pl)
{
    const int slice = blockIdx.x & 7;
    const int chunk = blockIdx.x >> 3;
    const int w = threadIdx.x >> 6;
    const int lane = threadIdx.x & 63;
    const int c0 = slice * 128 + lane * 2;
    const float a0 = att[c0];
    const float a1 = att[c0 + 1];
    const int d0 = (chunk * 4 + w) * 16;

    for (int di = 0; di < 16; ++di) {
        int d = d0 + di;
        int st = rs[d];
        int de = clampi(rs[d + 1] - st, 1, 64);
        st = __builtin_amdgcn_readfirstlane(clampi(st, 0, ET - 1));
        de = __builtin_amdgcn_readfirstlane(de);
        // one coalesced metadata load per dst; broadcast via readlane
        int msrc = csrc[st + ((lane < de) ? lane : de - 1)];
        msrc = clampi(msrc, 0, NN - 1);
        // xr channel pair for this dst
        unsigned xrp = *(const unsigned*)(xr + (size_t)d * 1024 + c0);
        float r0 = sb2f((short)(xrp & 0xffff));
        float r1 = sb2f((short)(xrp >> 16));

        for (int base = 0; base < de; base += 4) {
            float part[4];
#pragma unroll
            for (int r = 0; r < 4; ++r) {
                int idx = base + r;
                if (idx > de - 1) idx = de - 1;
                int s = __builtin_amdgcn_readlane(msrc, idx);
                unsigned xp = *(const unsigned*)(xl + (size_t)s * 1024 + c0);
                float x0 = sb2f((short)(xp & 0xffff));
                float x1 = sb2f((short)(xp >> 16));
                float u0 = x0 + r0; u0 = (u0 >= 0.f) ? u0 : 0.2f * u0;
                float u1 = x1 + r1; u1 = (u1 >= 0.f) ? u1 : 0.2f * u1;
                part[r] = fmaf(a0, u0, a1 * u1);
            }
#pragma unroll
            for (int msk = 32; msk; msk >>= 1) {
#pragma unroll
                for (int r = 0; r < 4; ++r)
                    part[r] += __shfl_xor(part[r], msk);
            }
            if (lane == 0) {
#pragma unroll
                for (int r = 0; r < 4; ++r)
                    if (base + r < de)
                        pl[(size_t)slice * ET + st + base + r] = part[r];
            }
        }
    }
}

// pass 2: per (dst, head): sum the 4 slice-partials -> logit; softmax ->
// unnormalized alpha (al) + denominator (dden). thread per dst.
__global__ __launch_bounds__(256) void gat_alpha1024(
    const float* __restrict__ pl, const int* __restrict__ rs,
    float* __restrict__ al, float* __restrict__ dden)
{
    int d = blockIdx.x * 256 + threadIdx.x;
    int st = rs[d];
    int de = clampi(rs[d + 1] - st, 1, 64);
    st = clampi(st, 0, ET - 1);
#pragma unroll
    for (int h = 0; h < 2; ++h) {
        float m = -1e30f;
        for (int i = 0; i < de; ++i) {
            float l = 0.f;
#pragma unroll
            for (int s = 0; s < 4; ++s)
                l += pl[(size_t)(h * 4 + s) * ET + st + i];
            m = fmaxf(m, l);
        }
        float den = 0.f;
        for (int i = 0; i < de; ++i) {
            float l = 0.f;
#pragma unroll
            for (int s = 0; s < 4; ++s)
                l += pl[(size_t)(h * 4 + s) * ET + st + i];
            float p = __expf(l - m);
            al[(size_t)h * ET + st + i] = p;
            den += p;
        }
        dden[h * NN + d] = den;
    }
}

// pass 3: out[dst, slice] = (sum_e al*xl[src,slice]) / den + bias, LeakyReLU.
// Same grid/XCD mapping as pass 1.
__global__ __launch_bounds__(256) void gat_wsum1024(
    const bf16* __restrict__ xl, const float* __restrict__ al,
    const float* __restrict__ dden, const float* __restrict__ bias,
    const int* __restrict__ rs, const int* __restrict__ csrc,
    bf16* __restrict__ hb)
{
    const int slice = blockIdx.x & 7;
    const int chunk = blockIdx.x >> 3;
    const int h = slice >> 2;
    const int w = threadIdx.x >> 6;
    const int lane = threadIdx.x & 63;
    const int c0 = slice * 128 + lane * 2;
    const float b0 = bias[c0];
    const float b1 = bias[c0 + 1];
    const int d0 = (chunk * 4 + w) * 16;

    for (int di = 0; di < 16; ++di) {
        int d = d0 + di;
        int st = rs[d];
        int de = clampi(rs[d + 1] - st, 1, 64);
        st = __builtin_amdgcn_readfirstlane(clampi(st, 0, ET - 1));
        de = __builtin_amdgcn_readfirstlane(de);
        int msrc = csrc[st + ((lane < de) ? lane : de - 1)];
        msrc = clampi(msrc, 0, NN - 1);
        float inv = 1.f / dden[h * NN + d];

        float acc0 = 0.f, acc1 = 0.f;
        for (int base = 0; base < de; base += 4) {
#pragma unroll
            for (int r = 0; r < 4; ++r) {
                int idx = base + r;
                bool ok = idx < de;
                if (!ok) idx = de - 1;
                int s = __builtin_amdgcn_readlane(msrc, idx);
                float wgt = ok ? al[(size_t)h * ET + st + idx] : 0.f;
                unsigned xp = *(const unsigned*)(xl + (size_t)s * 1024 + c0);
                acc0 = fmaf(wgt, sb2f((short)(xp & 0xffff)), acc0);
                acc1 = fmaf(wgt, sb2f((short)(xp >> 16)), acc1);
            }
        }
        float v0 = fmaf(acc0, inv, b0); v0 = (v0 >= 0.f) ? v0 : 0.01f * v0;
        float v1 = fmaf(acc1, inv, b1); v1 = (v1 >= 0.f) ? v1 : 0.01f * v1;
        unsigned o = (unsigned)(unsigned short)f2bs(v0) |
                     ((unsigned)(unsigned short)f2bs(v1) << 16);
        *(unsigned*)(hb + (size_t)d * 1024 + c0) = o;
    }
}

// ---------------------------------------------------------------------------
// GATv2 fused wave kernel (kept for L4 / HC=512: residual + LN-sums fusion).
// ---------------------------------------------------------------------------
template<int NH>
__global__ __launch_bounds__(256, 4) void gat_wave6(
    const bf16* __restrict__ xl, const bf16* __restrict__ xr,
    const float* __restrict__ att, const float* __restrict__ bias,
    const int* __restrict__ rs, const int* __restrict__ csrc,
    const float* __restrict__ res, float* __restrict__ out_f,
    bf16* __restrict__ out_b, float* __restrict__ lnsums)
{
    constexpr int HC = NH * 512;
    constexpr int PF = 6;
    constexpr int NODES = (NH == 2) ? 8 : 4;
    const int tid = threadIdx.x;
    const int w = tid >> 6;
    const int lane = tid & 63;
    const int wave_id = blockIdx.x * 4 + w;

    int msrc[NODES];
    int sdeg[NODES];
#pragma unroll
    for (int it = 0; it < NODES; ++it) {
        int gw = wave_id * NODES + it;
        int n = (NH == 2) ? (gw >> 1) : gw;
        int st = rs[n];
        int deg = clampi(rs[n + 1] - st, 1, 64);
        st = clampi(st, 0, ET - 1);
        st = __builtin_amdgcn_readfirstlane(st);
        deg = __builtin_amdgcn_readfirstlane(deg);
        sdeg[it] = deg;
        msrc[it] = csrc[st + ((lane < deg) ? lane : deg - 1)];
    }

    float av0[8], av1[8];
    {
        f32x4 t0 = *(const f32x4*)(att + lane * 8);
        f32x4 t1 = *(const f32x4*)(att + lane * 8 + 4);
#pragma unroll
        for (int k = 0; k < 4; k++) { av0[k] = t0[k]; av0[4 + k] = t1[k]; }
        if (NH == 2) {
            f32x4 t2 = *(const f32x4*)(att + 512 + lane * 8);
            f32x4 t3 = *(const f32x4*)(att + 512 + lane * 8 + 4);
#pragma unroll
            for (int k = 0; k < 4; k++) { av1[k] = t2[k]; av1[4 + k] = t3[k]; }
        } else {
#pragma unroll
            for (int k = 0; k < 8; k++) av1[k] = av0[k];
        }
    }

    f32x4 rows[2][PF];
    f32x4 rpx[2];

    auto issue = [&](int it, int pb) {
        int gw = wave_id * NODES + it;
        int n = (NH == 2) ? (gw >> 1) : gw;
        int h = (NH == 2) ? (gw & 1) : 0;
        int cb = h * 512 + lane * 8;
        rpx[pb] = *(const f32x4*)(xr + (size_t)n * HC + cb);
        int dm1 = sdeg[it] - 1;
#pragma unroll
        for (int r = 0; r < PF; r++) {
            int idx = (r < dm1) ? r : dm1;
            int s = __builtin_amdgcn_readlane(msrc[it], idx);
            s = clampi(s, 0, NN - 1);
            rows[pb][r] = *(const f32x4*)(xl + (size_t)s * HC + cb);
        }
    };

    auto compute = [&](int it, int pb) {
        int gw = wave_id * NODES + it;
        int n = (NH == 2) ? (gw >> 1) : gw;
        int h = (NH == 2) ? (gw & 1) : 0;
        int cb = h * 512 + lane * 8;
        int deg = sdeg[it];

        float rv[8], av[8];
        {
            bf16x8 xb = __builtin_bit_cast(bf16x8, rpx[pb]);
#pragma unroll
            for (int k = 0; k < 8; k++) {
                rv[k] = sb2f(xb[k]);
                av[k] = h ? av1[k] : av0[k];
            }
        }

        float part[PF];
#pragma unroll
        for (int r = 0; r < PF; r++) {
            bf16x8 rb = __builtin_bit_cast(bf16x8, rows[pb][r]);
            float p0 = 0.f, p1 = 0.f, p2 = 0.f, p3 = 0.f;
#pragma unroll
            for (int k = 0; k < 8; k += 4) {
                float x0 = sb2f(rb[k + 0]);
                float x1 = sb2f(rb[k + 1]);
                float x2 = sb2f(rb[k + 2]);
                float x3 = sb2f(rb[k + 3]);
                float u0 = x0 + rv[k + 0]; u0 = (u0 >= 0.f) ? u0 : 0.2f * u0;
                float u1 = x1 + rv[k + 1]; u1 = (u1 >= 0.f) ? u1 : 0.2f * u1;
                float u2 = x2 + rv[k + 2]; u2 = (u2 >= 0.f) ? u2 : 0.2f * u2;
                float u3 = x3 + rv[k + 3]; u3 = (u3 >= 0.f) ? u3 : 0.2f * u3;
                p0 = fmaf(av[k + 0], u0, p0);
                p1 = fmaf(av[k + 1], u1, p1);
                p2 = fmaf(av[k + 2], u2, p2);
                p3 = fmaf(av[k + 3], u3, p3);
            }
            part[r] = (p0 + p1) + (p2 + p3);
        }

#pragma unroll
        for (int msk = 32; msk; msk >>= 1) {
#pragma unroll
            for (int r = 0; r < PF; r++) part[r] += __shfl_xor(part[r], msk);
        }

        float m = -1e30f;
#pragma unroll
        for (int r = 0; r < PF; r++) {
            float vr = (r < deg) ? part[r] : -1e30f;
            m = fmaxf(m, vr);
        }
        float den = 0.f;
        float pw[PF];
#pragma unroll
        for (int r = 0; r < PF; r++) {
            float e = __expf(part[r] - m);
            pw[r] = (r < deg) ? e : 0.f;
            den += pw[r];
        }

        float acc[8];
#pragma unroll
        for (int k = 0; k < 8; k++) acc[k] = 0.f;
#pragma unroll
        for (int r = 0; r < PF; r++) {
            bf16x8 rb = __builtin_bit_cast(bf16x8, rows[pb][r]);
#pragma unroll
            for (int k = 0; k < 8; k++)
                acc[k] = fmaf(pw[r], sb2f(rb[k]), acc[k]);
        }

        if (deg > PF) {
            for (int i = PF; i < deg; i++) {
                int s = __builtin_amdgcn_readlane(msrc[it], i);
                s = clampi(s, 0, NN - 1);
                f32x4 rw = *(const f32x4*)(xl + (size_t)s * HC + cb);
                bf16x8 rb = __builtin_bit_cast(bf16x8, rw);
                float pt = 0.f;
#pragma unroll
                for (int k = 0; k < 8; k++) {
                    float x = sb2f(rb[k]);
                    float u = x + rv[k];
                    u = (u >= 0.f) ? u : 0.2f * u;
                    pt = fmaf(av[k], u, pt);
                }
#pragma unroll
                for (int msk = 32; msk; msk >>= 1) pt += __shfl_xor(pt, msk);
                float mn = fmaxf(m, pt);
                float rr = __expf(m - mn);
                float pi = __expf(pt - mn);
                m = mn;
                den = den * rr + pi;
#pragma unroll
                for (int k = 0; k < 8; k++) {
                    float x = sb2f(rb[k]);
                    acc[k] = fmaf(acc[k], rr, pi * x);
                }
            }
        }

        float inv = 1.f / den;
        f32x4 b0 = *(const f32x4*)(bias + cb);
        f32x4 b1 = *(const f32x4*)(bias + cb + 4);
        float vals[8];
#pragma unroll
        for (int k = 0; k < 8; k++) {
            float bv = (k < 4) ? b0[k] : b1[k - 4];
            float v = fmaf(acc[k], inv, bv);
            v = (v >= 0.f) ? v : 0.01f * v;
            vals[k] = v;
        }
        if (res) {
            float ls = 0.f, ls2 = 0.f;
#pragma unroll
            for (int k = 0; k < 8; k++) {
                vals[k] += res[(size_t)n * HC + cb + k];
                ls += vals[k];
                ls2 += vals[k] * vals[k];
            }
#pragma unroll
            for (int v = 0; v < 2; v++) {
                f32x4 ov;
#pragma unroll
                for (int k = 0; k < 4; k++) ov[k] = vals[v * 4 + k];
                *(f32x4*)(out_f + (size_t)n * HC + cb + v * 4) = ov;
            }
            if (lnsums) {
#pragma unroll
                for (int msk = 32; msk; msk >>= 1) {
                    ls += __shfl_xor(ls, msk);
                    ls2 += __shfl_xor(ls2, msk);
                }
                if (lane == 0) {
                    int g = n >> 8;
                    atomicAdd(&lnsums[g], ls);
                    atomicAdd(&lnsums[BBG + g], ls2);
                }
            }
        } else {
            bf16x8 ov;
#pragma unroll
            for (int k = 0; k < 8; k++) ov[k] = f2bs(vals[k]);
            *(bf16x8*)(out_b + (size_t)n * HC + cb) = ov;
        }
    };

    issue(0, 0);
#pragma unroll
    for (int it = 0; it < NODES; ++it) {
        int pb = it & 1;
        if (it + 1 < NODES) issue(it + 1, pb ^ 1);
        compute(it, pb);
    }
}

// ---------------------------------------------------------------------------
// LN apply + channel-wise online-softmax aggregation, node-chunked partials.
// ---------------------------------------------------------------------------
__global__ __launch_bounds__(256) void aggr_partial(
    const float* __restrict__ h, const float* __restrict__ lnsums,
    const float* __restrict__ lnw, const float* __restrict__ lnb,
    const float* __restrict__ t_, float* __restrict__ pm,
    float* __restrict__ pd, float* __restrict__ pa)
{
    int g = blockIdx.x, ch = blockIdx.y, nk = blockIdx.z;
    int tid = threadIdx.x;
    int c = ch * 256 + tid;
    const float tot = (float)(NG * DD);
    float S = lnsums[g], S2 = lnsums[BBG + g];
    float mu = S / tot;
    float iv = rsqrtf(fmaxf(S2 / tot - mu * mu, 0.f) + 1e-5f);
    float w = lnw[c], b = lnb[c], t = t_[0];
    size_t base = (size_t)g * NG * DD + (size_t)nk * 32 * DD + c;
    float m = -1e30f, den = 0.f, acc = 0.f;
    for (int i = 0; i < 32; i++) {
        float hn = (h[base + (size_t)i * DD] - mu) * iv * w + b;
        float lg = hn * t;
        if (lg > m) {
            float r = __expf(m - lg);
            den *= r; acc *= r; m = lg;
        }
        float p = __expf(lg - m);
        den += p; acc += p * hn;
    }
    size_t idx = (((size_t)g * 2 + ch) * 8 + nk) * 256 + tid;
    pm[idx] = m; pd[idx] = den; pa[idx] = acc;
}

__global__ __launch_bounds__(256) void aggr_combine(
    const float* __restrict__ pm, const float* __restrict__ pd,
    const float* __restrict__ pa, float* __restrict__ gout)
{
    int g = blockIdx.x, ch = blockIdx.y;
    int tid = threadIdx.x;
    size_t base = (((size_t)g * 2 + ch) * 8) * 256 + tid;
    float m = -1e30f;
#pragma unroll
    for (int k = 0; k < 8; k++) m = fmaxf(m, pm[base + k * 256]);
    float den = 0.f, acc = 0.f;
#pragma unroll
    for (int k = 0; k < 8; k++) {
        float r = __expf(pm[base + k * 256] - m);
        den += pd[base + k * 256] * r;
        acc += pa[base + k * 256] * r;
    }
    gout[(size_t)g * DD + ch * 256 + tid] = acc / den;
}

// ---------------------------------------------------------------------------
extern "C" void kernel_launch(void* const* d_in, const int* in_sizes, int n_in,
                              void* d_out, int out_size, void* d_ws, size_t ws_size,
                              hipStream_t stream)
{
    const float* x      = (const float*)d_in[0];
    const int*   ei     = (const int*)d_in[1];
    const float* xt_w1  = (const float*)d_in[3];
    const float* xt_b1  = (const float*)d_in[4];
    const float* xt_w2  = (const float*)d_in[5];
    const float* xt_b2  = (const float*)d_in[6];
    const float* ln_w   = (const float*)d_in[27];
    const float* ln_b   = (const float*)d_in[28];
    const float* aggr_t = (const float*)d_in[29];
    const float* m_w1   = (const float*)d_in[30];
    const float* m_b1   = (const float*)d_in[31];
    const float* m_w2   = (const float*)d_in[32];
    const float* m_b2   = (const float*)d_in[33];
    const float* m_w3   = (const float*)d_in[34];
    const float* m_b3   = (const float*)d_in[35];
    float* out = (float*)d_out;

    // ---- workspace layout (256B aligned); ints first ----
    char* p = (char*)d_ws;
    auto take = [&](size_t bytes) {
        char* r = p;
        p += (bytes + 255) & ~(size_t)255;
        return r;
    };
    int* i_deg     = (int*)take((size_t)(NN + 1) * 4);
    int* i_rs      = (int*)take((size_t)(NN + 1) * 4);
    int* i_cur     = (int*)take((size_t)NN * 4);
    int* i_src     = (int*)take((size_t)ET * 4);
    float* f_sums  = (float*)take((size_t)2 * BBG * 4);
    float* f_pm    = (float*)take((size_t)BBG * 2 * 8 * 256 * 4);
    float* f_pd    = (float*)take((size_t)BBG * 2 * 8 * 256 * 4);
    float* f_pa    = (float*)take((size_t)BBG * 2 * 8 * 256 * 4);
    float* f_pl    = (float*)take((size_t)8 * ET * 4);   // slice partial logits
    float* f_al    = (float*)take((size_t)2 * ET * 4);   // unnormalized alpha
    float* f_dden  = (float*)take((size_t)2 * NN * 4);   // softmax denominators
    float* b_g     = (float*)take((size_t)BBG * DD * 4);
    float* b_m1    = (float*)take((size_t)BBG * 384 * 4);
    float* b_m2    = (float*)take((size_t)BBG * 256 * 4);
    float* b_res   = (float*)take((size_t)NN * DD * 4);
    float* b_h     = (float*)take((size_t)NN * DD * 4);
    bf16* b_resb   = (bf16*)take((size_t)NN * DD * 2);
    bf16* b_hb     = (bf16*)take((size_t)NN * 1024 * 2);
    bf16* b_xlb    = (bf16*)take((size_t)NN * 1024 * 2);
    bf16* b_xrb    = (bf16*)take((size_t)NN * 1024 * 2);
    bf16* b_xb     = (bf16*)take((size_t)2 * NN * 32 * 2);
    bf16* b_wcat   = (bf16*)take((size_t)2048 * 1024 * 2);  // [wlT; wrT]
    bf16* b_w1b    = (bf16*)take((size_t)32 * 256 * 2);
    bf16* b_w2b    = (bf16*)take((size_t)256 * 256 * 2);
    bf16* b_t1b = b_hb;

    dim3 blk(256);

    // ---- CSR build + LN-sum zero ----
    hipMemsetAsync(i_deg, 0, (size_t)(NN + 1) * 4, stream);
    hipMemsetAsync(i_cur, 0, (size_t)NN * 4, stream);
    hipMemsetAsync(f_sums, 0, (size_t)2 * BBG * 4, stream);
    count_deg<<<ET / 256, blk, 0, stream>>>(ei, i_deg);
    scan_deg<<<1, blk, 0, stream>>>(i_deg, i_rs);
    fill_csr<<<ET / 256, blk, 0, stream>>>(ei, i_rs, i_cur, i_src);

    // ---- weight converts for x_trans + x convert ----
    f2b_vec<<<(2 * NN * 32 + 255) / 256, blk, 0, stream>>>(x, b_xb, 2 * NN * 32);
    transpose_f2b2<<<dim3(256 / 32, 32 / 32, 1), blk, 0, stream>>>(
        xt_w1, b_w1b, xt_w1, b_w1b, 32, 256);
    transpose_f2b2<<<dim3(256 / 32, 256 / 32, 1), blk, 0, stream>>>(
        xt_w2, b_w2b, xt_w2, b_w2b, 256, 256);

    // ---- x_trans ----
    gemm_mfma_bt<<<dim3(256 / 128, 32768 / 128), blk, 0, stream>>>(
        b_xb, b_w1b, xt_b1, (float*)nullptr, b_t1b, 32768, 256, 32, 0.01f, 1);
    gemm_mfma_bt<<<dim3(256 / 128, 32768 / 128), blk, 0, stream>>>(
        b_t1b, b_w2b, xt_b2, b_res, b_resb, 32768, 256, 256, 0.f, 0);

    // ---- 5 GATv2 layers ----
    for (int L = 0; L < 5; L++) {
        const float* wl  = (const float*)d_in[7 + 4 * L];
        const float* wr  = (const float*)d_in[8 + 4 * L];
        const float* att = (const float*)d_in[9 + 4 * L];
        const float* gb  = (const float*)d_in[10 + 4 * L];
        int Fin = (L == 0) ? 512 : 1024;
        int HC  = (L == 4) ? 512 : 1024;
        const bf16* hin = (L == 0) ? b_resb : b_hb;

        transpose_f2b2<<<dim3(HC / 32, Fin / 32, 2), blk, 0, stream>>>(
            wl, b_wcat, wr, b_wcat + (size_t)HC * Fin, Fin, HC);
        gemm_mfma_dual<<<dim3(2 * HC / 128, NN / 128), blk, 0, stream>>>(
            hin, b_wcat, b_xlb, b_xrb, NN, 2 * HC, Fin, HC);
        if (L == 4) {
            gat_wave6<1><<<1024, blk, 0, stream>>>(
                b_xlb, b_xrb, att, gb, i_rs, i_src,
                b_res, b_h, (bf16*)nullptr, f_sums);
        } else {
            gat_logit1024<<<2048, blk, 0, stream>>>(
                b_xlb, b_xrb, att, i_rs, i_src, f_pl);
            gat_alpha1024<<<NN / 256, blk, 0, stream>>>(
                f_pl, i_rs, f_al, f_dden);
            gat_wsum1024<<<2048, blk, 0, stream>>>(
                b_xlb, f_al, f_dden, gb, i_rs, i_src, b_hb);
        }
    }

    // ---- graph LN + softmax aggregation (single pass + combine) ----
    aggr_partial<<<dim3(BBG, 2, 8), blk, 0, stream>>>(
        b_h, f_sums, ln_w, ln_b, aggr_t, f_pm, f_pd, f_pa);
    aggr_combine<<<dim3(BBG, 2), blk, 0, stream>>>(f_pm, f_pd, f_pa, b_g);

    // ---- head MLP 512 -> 384 -> 256 -> 128 (fp32) ----
    gemm_f32<<<dim3(384 / 64, 1), blk, 0, stream>>>(
        b_g, m_w1, m_b1, b_m1, 64, 384, 512, 0.01f, 1);
    gemm_f32<<<dim3(256 / 64, 1), blk, 0, stream>>>(
        b_m1, m_w2, m_b2, b_m2, 64, 256, 384, 0.01f, 1);
    gemm_f32<<<dim3(128 / 64, 1), blk, 0, stream>>>(
        b_m2, m_w3, m_b3, out, 64, 128, 256, 0.f, 0);
}

// Round 6
// 1047.544 us; speedup vs baseline: 1.1816x; 1.1816x over previous
//
#include <hip/hip_runtime.h>
#include <hip/hip_bf16.h>

typedef __hip_bfloat16 bf16;

#define NN 16384          // gate nodes
#define BBG 64            // graphs
#define EE 49152          // directed edges (no self loops)
#define ET (EE + NN)      // edges + self loops = 65536
#define DD 512            // node feature dim (2F)
#define NG (NN / BBG)     // 256 nodes per graph

__device__ __forceinline__ float b2f(bf16 v) { return __bfloat162float(v); }
__device__ __forceinline__ bf16 f2b(float v) { return __float2bfloat16(v); }
__device__ __forceinline__ float sb2f(short s) {
    unsigned u = ((unsigned)(unsigned short)s) << 16;
    return __builtin_bit_cast(float, u);
}
__device__ __forceinline__ short f2bs(float v) {
    bf16 b = f2b(v);
    return __builtin_bit_cast(short, b);
}
__device__ __forceinline__ int clampi(int v, int lo, int hi)
{
    return v < lo ? lo : (v > hi ? hi : v);
}

typedef __attribute__((ext_vector_type(8))) short bf16x8;  // 8 bf16 = 4 VGPRs
typedef __attribute__((ext_vector_type(4))) float f32x4;

#define AS1 __attribute__((address_space(1)))
#define AS3 __attribute__((address_space(3)))

// ---------------------------------------------------------------------------
// MFMA bf16 GEMM (m97 structure): C[M,N] = act(A[M,K] @ Bt[N,K]^T + bias).
// ---------------------------------------------------------------------------
__global__ __launch_bounds__(256) void gemm_mfma_bt(
    const bf16* __restrict__ A, const bf16* __restrict__ Bt,
    const float* __restrict__ bias, float* __restrict__ C,
    bf16* __restrict__ Cb, int M, int N, int K, float slope, int has_act)
{
    __shared__ bf16 As[128 * 32];
    __shared__ bf16 Bs[128 * 32];
    const int tid = threadIdx.x;
    const int w = tid >> 6;
    const int l = tid & 63;
    const int bm = blockIdx.y * 128;
    const int bn = blockIdx.x * 128;
    const int wrow = (w >> 1) * 64;
    const int wcol = (w & 1) * 64;
    const int quad = l >> 4;
    const int c16 = l & 15;

    const int lrow = l >> 2;
    const int lchunk = l & 3;
    const bf16* Ag = A + (size_t)(bm + w * 16 + lrow) * K + lchunk * 8;
    const bf16* Bg = Bt + (size_t)(bn + w * 16 + lrow) * K + lchunk * 8;
    char* AsB = (char*)As;
    char* BsB = (char*)Bs;

    f32x4 acc[4][4] = {};

    for (int k0 = 0; k0 < K; k0 += 32) {
        __builtin_amdgcn_global_load_lds((const AS1 void*)(Ag + k0),
            (AS3 void*)(AsB + w * 1024), 16, 0, 0);
        __builtin_amdgcn_global_load_lds((const AS1 void*)(Ag + (size_t)64 * K + k0),
            (AS3 void*)(AsB + 4096 + w * 1024), 16, 0, 0);
        __builtin_amdgcn_global_load_lds((const AS1 void*)(Bg + k0),
            (AS3 void*)(BsB + w * 1024), 16, 0, 0);
        __builtin_amdgcn_global_load_lds((const AS1 void*)(Bg + (size_t)64 * K + k0),
            (AS3 void*)(BsB + 4096 + w * 1024), 16, 0, 0);
        __syncthreads();

        bf16x8 a[4], b[4];
#pragma unroll
        for (int i = 0; i < 4; i++) {
            int ra = wrow + i * 16 + c16;
            a[i] = *(const bf16x8*)(AsB + ra * 64 + quad * 16);
            int rb = wcol + i * 16 + c16;
            b[i] = *(const bf16x8*)(BsB + rb * 64 + quad * 16);
        }
#pragma unroll
        for (int i = 0; i < 4; i++)
#pragma unroll
            for (int j = 0; j < 4; j++)
                acc[i][j] = __builtin_amdgcn_mfma_f32_16x16x32_bf16(
                    a[i], b[j], acc[i][j], 0, 0, 0);
        __syncthreads();
    }

#pragma unroll
    for (int i = 0; i < 4; i++) {
#pragma unroll
        for (int j = 0; j < 4; j++) {
            int col = bn + wcol + j * 16 + c16;
            float bv = bias ? bias[col] : 0.f;
#pragma unroll
            for (int r = 0; r < 4; r++) {
                int row = bm + wrow + i * 16 + quad * 4 + r;
                float v = acc[i][j][r] + bv;
                if (has_act) v = (v >= 0.f) ? v : v * slope;
                if (C)  C[(size_t)row * N + col] = v;
                if (Cb) Cb[(size_t)row * N + col] = f2b(v);
            }
        }
    }
}

// ---------------------------------------------------------------------------
// Merged dual GEMM: Bt = [wlT; wrT] (Ntot=2*HC rows). cols [0,HC) -> X0 (xl),
// cols [HC,2HC) -> X1 (xr).
// ---------------------------------------------------------------------------
__global__ __launch_bounds__(256) void gemm_mfma_dual(
    const bf16* __restrict__ A, const bf16* __restrict__ Bt,
    bf16* __restrict__ X0, bf16* __restrict__ X1,
    int M, int Ntot, int K, int HC)
{
    __shared__ bf16 As[128 * 32];
    __shared__ bf16 Bs[128 * 32];
    const int tid = threadIdx.x;
    const int w = tid >> 6;
    const int l = tid & 63;
    const int bm = blockIdx.y * 128;
    const int bn = blockIdx.x * 128;
    const int wrow = (w >> 1) * 64;
    const int wcol = (w & 1) * 64;
    const int quad = l >> 4;
    const int c16 = l & 15;

    const int lrow = l >> 2;
    const int lchunk = l & 3;
    const bf16* Ag = A + (size_t)(bm + w * 16 + lrow) * K + lchunk * 8;
    const bf16* Bg = Bt + (size_t)(bn + w * 16 + lrow) * K + lchunk * 8;
    char* AsB = (char*)As;
    char* BsB = (char*)Bs;

    f32x4 acc[4][4] = {};

    for (int k0 = 0; k0 < K; k0 += 32) {
        __builtin_amdgcn_global_load_lds((const AS1 void*)(Ag + k0),
            (AS3 void*)(AsB + w * 1024), 16, 0, 0);
        __builtin_amdgcn_global_load_lds((const AS1 void*)(Ag + (size_t)64 * K + k0),
            (AS3 void*)(AsB + 4096 + w * 1024), 16, 0, 0);
        __builtin_amdgcn_global_load_lds((const AS1 void*)(Bg + k0),
            (AS3 void*)(BsB + w * 1024), 16, 0, 0);
        __builtin_amdgcn_global_load_lds((const AS1 void*)(Bg + (size_t)64 * K + k0),
            (AS3 void*)(BsB + 4096 + w * 1024), 16, 0, 0);
        __syncthreads();

        bf16x8 a[4], b[4];
#pragma unroll
        for (int i = 0; i < 4; i++) {
            int ra = wrow + i * 16 + c16;
            a[i] = *(const bf16x8*)(AsB + ra * 64 + quad * 16);
            int rb = wcol + i * 16 + c16;
            b[i] = *(const bf16x8*)(BsB + rb * 64 + quad * 16);
        }
#pragma unroll
        for (int i = 0; i < 4; i++)
#pragma unroll
            for (int j = 0; j < 4; j++)
                acc[i][j] = __builtin_amdgcn_mfma_f32_16x16x32_bf16(
                    a[i], b[j], acc[i][j], 0, 0, 0);
        __syncthreads();
    }

#pragma unroll
    for (int i = 0; i < 4; i++) {
#pragma unroll
        for (int j = 0; j < 4; j++) {
            int col = bn + wcol + j * 16 + c16;
            bf16* dst = (col < HC) ? (X0 + col) : (X1 + col - HC);
#pragma unroll
            for (int r = 0; r < 4; r++) {
                int row = bm + wrow + i * 16 + quad * 4 + r;
                dst[(size_t)row * HC] = f2b(acc[i][j][r]);
            }
        }
    }
}

// ---------------------------------------------------------------------------
// fp32 GEMM (head MLP only)
// ---------------------------------------------------------------------------
__global__ __launch_bounds__(256) void gemm_f32(
    const float* __restrict__ A, const float* __restrict__ W,
    const float* __restrict__ bias, float* __restrict__ C,
    int M, int N, int K, float slope, int has_act)
{
    const int BK = 16;
    __shared__ float Asm[BK][64 + 1];
    __shared__ float Wsm[BK][64 + 1];
    int tid = threadIdx.x;
    int bm = blockIdx.y * 64;
    int bn = blockIdx.x * 64;
    int tr = tid >> 4;
    int tc = tid & 15;
    float acc[4][4] = {};

    for (int k0 = 0; k0 < K; k0 += BK) {
        {
            int col = tid & 15;
            int row = tid >> 4;
#pragma unroll
            for (int p = 0; p < 4; p++) {
                int r = row + p * 16;
                Asm[col][r] = A[(size_t)(bm + r) * K + k0 + col];
            }
        }
        {
            int wc = tid & 63;
            int wr = tid >> 6;
#pragma unroll
            for (int p = 0; p < 4; p++) {
                int r = wr + p * 4;
                Wsm[r][wc] = W[(size_t)(k0 + r) * N + bn + wc];
            }
        }
        __syncthreads();
#pragma unroll
        for (int kk = 0; kk < BK; kk++) {
            float a[4], w[4];
#pragma unroll
            for (int i = 0; i < 4; i++) a[i] = Asm[kk][tr * 4 + i];
#pragma unroll
            for (int j = 0; j < 4; j++) w[j] = Wsm[kk][tc * 4 + j];
#pragma unroll
            for (int i = 0; i < 4; i++)
#pragma unroll
                for (int j = 0; j < 4; j++)
                    acc[i][j] += a[i] * w[j];
        }
        __syncthreads();
    }
#pragma unroll
    for (int i = 0; i < 4; i++) {
        int r = bm + tr * 4 + i;
#pragma unroll
        for (int j = 0; j < 4; j++) {
            int cn = bn + tc * 4 + j;
            float v = acc[i][j];
            if (bias) v += bias[cn];
            if (has_act) v = (v >= 0.f) ? v : v * slope;
            C[(size_t)r * N + cn] = v;
        }
    }
}

// ---------------------------------------------------------------------------
// Batched fp32 [R,C] -> bf16 [C,R] transpose-convert (z selects tensor pair)
// ---------------------------------------------------------------------------
__global__ __launch_bounds__(256) void transpose_f2b2(
    const float* __restrict__ in0, bf16* __restrict__ out0,
    const float* __restrict__ in1, bf16* __restrict__ out1, int R, int C)
{
    const float* in = blockIdx.z ? in1 : in0;
    bf16* out = blockIdx.z ? out1 : out0;
    __shared__ float tile[32][33];
    int c0 = blockIdx.x * 32;
    int r0 = blockIdx.y * 32;
    int tx = threadIdx.x & 31;
    int ty = threadIdx.x >> 5;
#pragma unroll
    for (int k = 0; k < 4; k++) {
        int r = ty + k * 8;
        tile[r][tx] = in[(size_t)(r0 + r) * C + c0 + tx];
    }
    __syncthreads();
#pragma unroll
    for (int k = 0; k < 4; k++) {
        int rr = ty + k * 8;
        out[(size_t)(c0 + rr) * R + r0 + tx] = f2b(tile[tx][rr]);
    }
}

__global__ void f2b_vec(const float* __restrict__ in, bf16* __restrict__ out, int n)
{
    int i = blockIdx.x * 256 + threadIdx.x;
    if (i < n) out[i] = f2b(in[i]);
}

// ---------------------------------------------------------------------------
// CSR build over dst (self loops: edge ids [EE, ET) are node e-EE)
// ---------------------------------------------------------------------------
__global__ void count_deg(const int* __restrict__ ei, int* __restrict__ deg)
{
    int e = blockIdx.x * 256 + threadIdx.x;
    if (e >= ET) return;
    int d = (e < EE) ? ei[EE + e] : (e - EE);
    d = clampi(d, 0, NN - 1);
    atomicAdd(&deg[d], 1);
}

__global__ __launch_bounds__(256) void scan_deg(const int* __restrict__ deg,
                                                int* __restrict__ rs)
{
    __shared__ int part[256];
    __shared__ int psum[257];
    int tid = threadIdx.x;
    const int per = NN / 256;
    int base = tid * per;
    int s = 0;
    for (int i = 0; i < per; i++) s += deg[base + i];
    part[tid] = s;
    __syncthreads();
    if (tid == 0) {
        int acc = 0;
        for (int i = 0; i < 256; i++) { psum[i] = acc; acc += part[i]; }
        psum[256] = acc;
    }
    __syncthreads();
    int acc = psum[tid];
    for (int i = 0; i < per; i++) { rs[base + i] = acc; acc += deg[base + i]; }
    if (tid == 0) rs[NN] = psum[256];
}

__global__ void fill_csr(const int* __restrict__ ei, const int* __restrict__ rs,
                         int* __restrict__ cur, int* __restrict__ csrc)
{
    int e = blockIdx.x * 256 + threadIdx.x;
    if (e >= ET) return;
    int s, d;
    if (e < EE) { s = ei[e]; d = ei[EE + e]; } else { s = d = e - EE; }
    s = clampi(s, 0, NN - 1);
    d = clampi(d, 0, NN - 1);
    int pos = atomicAdd(&cur[d], 1);
    int slot = clampi(rs[d] + pos, 0, ET - 1);
    csrc[slot] = s;
}

// ---------------------------------------------------------------------------
// GATv2 edge phase v10: LDS-staged async pipeline with MANUAL counted vmcnt.
// Post-mortem R2-R5: VGPR pinned at 64 in every round proves the compiler
// collapses any register prefetch buffer (rows[2][6] alone needs 56 VGPRs)
// -> ~1-2 loads in flight/CU -> the invariant ~1.5 TB/s. Fix: stage rows in
// LDS via global_load_lds (zero VGPR cost, fire-and-forget, compiler cannot
// collapse) + asm "s_waitcnt vmcnt(N)" with N = loads-per-node so the NEXT
// node's loads stay in flight across compute (T4: never drain to 0 mid-loop).
// Each gathered row slice is lane-contiguous 1KB = exactly one
// global_load_lds dwordx4 (dest = base + lane*16, m104 layout = identity).
// NH=2: 4-wave blocks, 7 slots/buf (xr + 6 rows) -> 56KB LDS.
// NH=1: 2-wave blocks, 9 slots (.. + res 2KB)    -> 36KB LDS.
// ---------------------------------------------------------------------------
template<int NH>   // NH=2: HC=1024 (L0-3). NH=1: HC=512 (L4, res+LN fused).
__global__ __launch_bounds__(256) void gat_wave7(
    const bf16* __restrict__ xl, const bf16* __restrict__ xr,
    const float* __restrict__ att, const float* __restrict__ bias,
    const int* __restrict__ rs, const int* __restrict__ csrc,
    const float* __restrict__ res, float* __restrict__ out_f,
    bf16* __restrict__ out_b, float* __restrict__ lnsums)
{
    constexpr int HC = NH * 512;
    constexpr int PF = 6;
    constexpr int NODES = (NH == 2) ? 8 : 4;    // node-heads per wave
    constexpr int WPB = (NH == 2) ? 4 : 2;      // waves per block
    constexpr int SLOTS = (NH == 2) ? 7 : 9;    // 1KB slots per buffer
    __shared__ char smem[WPB * 2 * SLOTS * 1024];

    const int tid = threadIdx.x;
    const int w = tid >> 6;
    const int lane = tid & 63;
    const int wave_id = blockIdx.x * WPB + w;   // 0..4095

    // ---- metadata: all NODES csrc rows up-front (coalesced) ----
    int msrc[NODES];
    int sdeg[NODES];
#pragma unroll
    for (int it = 0; it < NODES; ++it) {
        int gw = wave_id * NODES + it;
        int n = (NH == 2) ? (gw >> 1) : gw;
        int st = rs[n];
        int deg = clampi(rs[n + 1] - st, 1, 64);
        st = clampi(st, 0, ET - 1);
        st = __builtin_amdgcn_readfirstlane(st);
        deg = __builtin_amdgcn_readfirstlane(deg);
        sdeg[it] = deg;
        msrc[it] = csrc[st + ((lane < deg) ? lane : deg - 1)];
    }

    // ---- loop-invariant preloads: att + bias (both head variants) ----
    float av0[8], av1[8], bv0[8], bv1[8];
    {
        f32x4 t0 = *(const f32x4*)(att + lane * 8);
        f32x4 t1 = *(const f32x4*)(att + lane * 8 + 4);
        f32x4 u0 = *(const f32x4*)(bias + lane * 8);
        f32x4 u1 = *(const f32x4*)(bias + lane * 8 + 4);
#pragma unroll
        for (int k = 0; k < 4; k++) {
            av0[k] = t0[k]; av0[4 + k] = t1[k];
            bv0[k] = u0[k]; bv0[4 + k] = u1[k];
        }
        if (NH == 2) {
            f32x4 t2 = *(const f32x4*)(att + 512 + lane * 8);
            f32x4 t3 = *(const f32x4*)(att + 512 + lane * 8 + 4);
            f32x4 u2 = *(const f32x4*)(bias + 512 + lane * 8);
            f32x4 u3 = *(const f32x4*)(bias + 512 + lane * 8 + 4);
#pragma unroll
            for (int k = 0; k < 4; k++) {
                av1[k] = t2[k]; av1[4 + k] = t3[k];
                bv1[k] = u2[k]; bv1[4 + k] = u3[k];
            }
        } else {
#pragma unroll
            for (int k = 0; k < 8; k++) { av1[k] = av0[k]; bv1[k] = bv0[k]; }
        }
    }

    // ---- async stage of one node-head into LDS buffer pb ----
    auto issue = [&](int it, int pb) {
        int gw = wave_id * NODES + it;
        int n = (NH == 2) ? (gw >> 1) : gw;
        int h = (NH == 2) ? (gw & 1) : 0;
        char* buf = smem + (size_t)((w * 2 + pb) * SLOTS) * 1024;
        const bf16* xrrow = xr + (size_t)n * HC + h * 512 + lane * 8;
        __builtin_amdgcn_global_load_lds((const AS1 void*)xrrow,
            (AS3 void*)buf, 16, 0, 0);
        int dm1 = sdeg[it] - 1;
#pragma unroll
        for (int r = 0; r < PF; r++) {
            int idx = (r < dm1) ? r : dm1;
            int s = __builtin_amdgcn_readlane(msrc[it], idx);
            s = clampi(s, 0, NN - 1);
            const bf16* row = xl + (size_t)s * HC + h * 512 + lane * 8;
            __builtin_amdgcn_global_load_lds((const AS1 void*)row,
                (AS3 void*)(buf + (1 + r) * 1024), 16, 0, 0);
        }
        if (NH == 1) {  // stage residual (fp32, 2KB) too: keeps loop vmem pure
            const float* rr = res + (size_t)n * 512 + lane * 4;
            __builtin_amdgcn_global_load_lds((const AS1 void*)rr,
                (AS3 void*)(buf + 7 * 1024), 16, 0, 0);
            __builtin_amdgcn_global_load_lds((const AS1 void*)(rr + 256),
                (AS3 void*)(buf + 8 * 1024), 16, 0, 0);
        }
    };

    auto compute = [&](int it, int pb) {
        int gw = wave_id * NODES + it;
        int n = (NH == 2) ? (gw >> 1) : gw;
        int h = (NH == 2) ? (gw & 1) : 0;
        int cb = h * 512 + lane * 8;
        int deg = sdeg[it];
        char* buf = smem + (size_t)((w * 2 + pb) * SLOTS) * 1024;

        float rv[8], av[8];
        {
            bf16x8 xb = *(const bf16x8*)(buf + lane * 16);
#pragma unroll
            for (int k = 0; k < 8; k++) {
                rv[k] = sb2f(xb[k]);
                av[k] = h ? av1[k] : av0[k];
            }
        }
        // read rows once into registers (used by dot AND accumulate)
        bf16x8 rloc[PF];
#pragma unroll
        for (int r = 0; r < PF; r++)
            rloc[r] = *(const bf16x8*)(buf + (1 + r) * 1024 + lane * 16);

        // Phase A: per-edge dots (independent chains)
        float part[PF];
#pragma unroll
        for (int r = 0; r < PF; r++) {
            float p0 = 0.f, p1 = 0.f, p2 = 0.f, p3 = 0.f;
#pragma unroll
            for (int k = 0; k < 8; k += 4) {
                float x0 = sb2f(rloc[r][k + 0]);
                float x1 = sb2f(rloc[r][k + 1]);
                float x2 = sb2f(rloc[r][k + 2]);
                float x3 = sb2f(rloc[r][k + 3]);
                float u0 = x0 + rv[k + 0]; u0 = (u0 >= 0.f) ? u0 : 0.2f * u0;
                float u1 = x1 + rv[k + 1]; u1 = (u1 >= 0.f) ? u1 : 0.2f * u1;
                float u2 = x2 + rv[k + 2]; u2 = (u2 >= 0.f) ? u2 : 0.2f * u2;
                float u3 = x3 + rv[k + 3]; u3 = (u3 >= 0.f) ? u3 : 0.2f * u3;
                p0 = fmaf(av[k + 0], u0, p0);
                p1 = fmaf(av[k + 1], u1, p1);
                p2 = fmaf(av[k + 2], u2, p2);
                p3 = fmaf(av[k + 3], u3, p3);
            }
            part[r] = (p0 + p1) + (p2 + p3);
        }

        // Phase B: full-wave butterfly, PF independent chains interleaved
#pragma unroll
        for (int msk = 32; msk; msk >>= 1) {
#pragma unroll
            for (int r = 0; r < PF; r++) part[r] += __shfl_xor(part[r], msk);
        }

        // Phase C: batched max / exp / denominator (invalid rows masked)
        float m = -1e30f;
#pragma unroll
        for (int r = 0; r < PF; r++) {
            float vr = (r < deg) ? part[r] : -1e30f;
            m = fmaxf(m, vr);
        }
        float den = 0.f;
        float pw[PF];
#pragma unroll
        for (int r = 0; r < PF; r++) {
            float e = __expf(part[r] - m);
            pw[r] = (r < deg) ? e : 0.f;
            den += pw[r];
        }

        // Phase D: weighted accumulate
        float acc[8];
#pragma unroll
        for (int k = 0; k < 8; k++) acc[k] = 0.f;
#pragma unroll
        for (int r = 0; r < PF; r++) {
#pragma unroll
            for (int k = 0; k < 8; k++)
                acc[k] = fmaf(pw[r], sb2f(rloc[r][k]), acc[k]);
        }

        // rare tail (deg > PF, ~8% of nodes): register loads, online update
        // (compiler's own waits drain the pipeline here; acceptable, rare)
        if (deg > PF) {
            for (int i = PF; i < deg; i++) {
                int s = __builtin_amdgcn_readlane(msrc[it], i);
                s = clampi(s, 0, NN - 1);
                f32x4 rw = *(const f32x4*)(xl + (size_t)s * HC + cb);
                bf16x8 rb = __builtin_bit_cast(bf16x8, rw);
                float pt = 0.f;
#pragma unroll
                for (int k = 0; k < 8; k++) {
                    float x = sb2f(rb[k]);
                    float u = x + rv[k];
                    u = (u >= 0.f) ? u : 0.2f * u;
                    pt = fmaf(av[k], u, pt);
                }
#pragma unroll
                for (int msk = 32; msk; msk >>= 1) pt += __shfl_xor(pt, msk);
                float mn = fmaxf(m, pt);
                float rr = __expf(m - mn);
                float pi = __expf(pt - mn);
                m = mn;
                den = den * rr + pi;
#pragma unroll
                for (int k = 0; k < 8; k++) {
                    float x = sb2f(rb[k]);
                    acc[k] = fmaf(acc[k], rr, pi * x);
                }
            }
        }

        // epilogue
        float inv = 1.f / den;
        float vals[8];
#pragma unroll
        for (int k = 0; k < 8; k++) {
            float bv = h ? bv1[k] : bv0[k];
            float v = fmaf(acc[k], inv, bv);
            v = (v >= 0.f) ? v : 0.01f * v;
            vals[k] = v;
        }
        if (NH == 1) {   // L4: residual add (staged in LDS), fp32 out, LN sums
            f32x4 r0 = *(const f32x4*)(buf + 7 * 1024 + lane * 32);
            f32x4 r1 = *(const f32x4*)(buf + 7 * 1024 + lane * 32 + 16);
            float ls = 0.f, ls2 = 0.f;
#pragma unroll
            for (int k = 0; k < 8; k++) {
                vals[k] += (k < 4) ? r0[k] : r1[k - 4];
                ls += vals[k];
                ls2 += vals[k] * vals[k];
            }
#pragma unroll
            for (int v = 0; v < 2; v++) {
                f32x4 ov;
#pragma unroll
                for (int k = 0; k < 4; k++) ov[k] = vals[v * 4 + k];
                *(f32x4*)(out_f + (size_t)n * HC + cb + v * 4) = ov;
            }
#pragma unroll
            for (int msk = 32; msk; msk >>= 1) {
                ls += __shfl_xor(ls, msk);
                ls2 += __shfl_xor(ls2, msk);
            }
            if (lane == 0) {
                int g = n >> 8;
                atomicAdd(&lnsums[g], ls);
                atomicAdd(&lnsums[BBG + g], ls2);
            }
        } else {         // L0-3: bf16 out
            bf16x8 ov;
#pragma unroll
            for (int k = 0; k < 8; k++) ov[k] = f2bs(vals[k]);
            *(bf16x8*)(out_b + (size_t)n * HC + cb) = ov;
        }
    };

    // ---- pipelined main loop with counted vmcnt ----
    // Wait N = loads-per-node: the newest N vmem ops (next node's stage)
    // remain in flight; everything older (this node's stage) is drained.
    issue(0, 0);
#pragma unroll
    for (int it = 0; it < NODES; ++it) {
        int pb = it & 1;
        if (it + 1 < NODES) {
            issue(it + 1, pb ^ 1);
            if (NH == 2) asm volatile("s_waitcnt vmcnt(7)" ::: "memory");
            else         asm volatile("s_waitcnt vmcnt(9)" ::: "memory");
        } else {
            asm volatile("s_waitcnt vmcnt(0)" ::: "memory");
        }
        __builtin_amdgcn_sched_barrier(0);
        compute(it, pb);
    }
}

// ---------------------------------------------------------------------------
// LN apply + channel-wise online-softmax aggregation, node-chunked partials.
// ---------------------------------------------------------------------------
__global__ __launch_bounds__(256) void aggr_partial(
    const float* __restrict__ h, const float* __restrict__ lnsums,
    const float* __restrict__ lnw, const float* __restrict__ lnb,
    const float* __restrict__ t_, float* __restrict__ pm,
    float* __restrict__ pd, float* __restrict__ pa)
{
    int g = blockIdx.x, ch = blockIdx.y, nk = blockIdx.z;
    int tid = threadIdx.x;
    int c = ch * 256 + tid;
    const float tot = (float)(NG * DD);
    float S = lnsums[g], S2 = lnsums[BBG + g];
    float mu = S / tot;
    float iv = rsqrtf(fmaxf(S2 / tot - mu * mu, 0.f) + 1e-5f);
    float w = lnw[c], b = lnb[c], t = t_[0];
    size_t base = (size_t)g * NG * DD + (size_t)nk * 32 * DD + c;
    float m = -1e30f, den = 0.f, acc = 0.f;
    for (int i = 0; i < 32; i++) {
        float hn = (h[base + (size_t)i * DD] - mu) * iv * w + b;
        float lg = hn * t;
        if (lg > m) {
            float r = __expf(m - lg);
            den *= r; acc *= r; m = lg;
        }
        float p = __expf(lg - m);
        den += p; acc += p * hn;
    }
    size_t idx = (((size_t)g * 2 + ch) * 8 + nk) * 256 + tid;
    pm[idx] = m; pd[idx] = den; pa[idx] = acc;
}

__global__ __launch_bounds__(256) void aggr_combine(
    const float* __restrict__ pm, const float* __restrict__ pd,
    const float* __restrict__ pa, float* __restrict__ gout)
{
    int g = blockIdx.x, ch = blockIdx.y;
    int tid = threadIdx.x;
    size_t base = (((size_t)g * 2 + ch) * 8) * 256 + tid;
    float m = -1e30f;
#pragma unroll
    for (int k = 0; k < 8; k++) m = fmaxf(m, pm[base + k * 256]);
    float den = 0.f, acc = 0.f;
#pragma unroll
    for (int k = 0; k < 8; k++) {
        float r = __expf(pm[base + k * 256] - m);
        den += pd[base + k * 256] * r;
        acc += pa[base + k * 256] * r;
    }
    gout[(size_t)g * DD + ch * 256 + tid] = acc / den;
}

// ---------------------------------------------------------------------------
extern "C" void kernel_launch(void* const* d_in, const int* in_sizes, int n_in,
                              void* d_out, int out_size, void* d_ws, size_t ws_size,
                              hipStream_t stream)
{
    const float* x      = (const float*)d_in[0];
    const int*   ei     = (const int*)d_in[1];
    const float* xt_w1  = (const float*)d_in[3];
    const float* xt_b1  = (const float*)d_in[4];
    const float* xt_w2  = (const float*)d_in[5];
    const float* xt_b2  = (const float*)d_in[6];
    const float* ln_w   = (const float*)d_in[27];
    const float* ln_b   = (const float*)d_in[28];
    const float* aggr_t = (const float*)d_in[29];
    const float* m_w1   = (const float*)d_in[30];
    const float* m_b1   = (const float*)d_in[31];
    const float* m_w2   = (const float*)d_in[32];
    const float* m_b2   = (const float*)d_in[33];
    const float* m_w3   = (const float*)d_in[34];
    const float* m_b3   = (const float*)d_in[35];
    float* out = (float*)d_out;

    // ---- workspace layout (256B aligned); ints first ----
    char* p = (char*)d_ws;
    auto take = [&](size_t bytes) {
        char* r = p;
        p += (bytes + 255) & ~(size_t)255;
        return r;
    };
    int* i_deg     = (int*)take((size_t)(NN + 1) * 4);
    int* i_rs      = (int*)take((size_t)(NN + 1) * 4);
    int* i_cur     = (int*)take((size_t)NN * 4);
    int* i_src     = (int*)take((size_t)ET * 4);
    float* f_sums  = (float*)take((size_t)2 * BBG * 4);
    float* f_pm    = (float*)take((size_t)BBG * 2 * 8 * 256 * 4);
    float* f_pd    = (float*)take((size_t)BBG * 2 * 8 * 256 * 4);
    float* f_pa    = (float*)take((size_t)BBG * 2 * 8 * 256 * 4);
    float* b_g     = (float*)take((size_t)BBG * DD * 4);
    float* b_m1    = (float*)take((size_t)BBG * 384 * 4);
    float* b_m2    = (float*)take((size_t)BBG * 256 * 4);
    float* b_res   = (float*)take((size_t)NN * DD * 4);
    float* b_h     = (float*)take((size_t)NN * DD * 4);
    bf16* b_resb   = (bf16*)take((size_t)NN * DD * 2);
    bf16* b_hb     = (bf16*)take((size_t)NN * 1024 * 2);
    bf16* b_xlb    = (bf16*)take((size_t)NN * 1024 * 2);
    bf16* b_xrb    = (bf16*)take((size_t)NN * 1024 * 2);
    bf16* b_xb     = (bf16*)take((size_t)2 * NN * 32 * 2);
    bf16* b_wcat   = (bf16*)take((size_t)2048 * 1024 * 2);  // [wlT; wrT]
    bf16* b_w1b    = (bf16*)take((size_t)32 * 256 * 2);
    bf16* b_w2b    = (bf16*)take((size_t)256 * 256 * 2);
    bf16* b_t1b = b_hb;

    dim3 blk(256);

    // ---- CSR build + LN-sum zero ----
    hipMemsetAsync(i_deg, 0, (size_t)(NN + 1) * 4, stream);
    hipMemsetAsync(i_cur, 0, (size_t)NN * 4, stream);
    hipMemsetAsync(f_sums, 0, (size_t)2 * BBG * 4, stream);
    count_deg<<<ET / 256, blk, 0, stream>>>(ei, i_deg);
    scan_deg<<<1, blk, 0, stream>>>(i_deg, i_rs);
    fill_csr<<<ET / 256, blk, 0, stream>>>(ei, i_rs, i_cur, i_src);

    // ---- weight converts for x_trans + x convert ----
    f2b_vec<<<(2 * NN * 32 + 255) / 256, blk, 0, stream>>>(x, b_xb, 2 * NN * 32);
    transpose_f2b2<<<dim3(256 / 32, 32 / 32, 1), blk, 0, stream>>>(
        xt_w1, b_w1b, xt_w1, b_w1b, 32, 256);
    transpose_f2b2<<<dim3(256 / 32, 256 / 32, 1), blk, 0, stream>>>(
        xt_w2, b_w2b, xt_w2, b_w2b, 256, 256);

    // ---- x_trans ----
    gemm_mfma_bt<<<dim3(256 / 128, 32768 / 128), blk, 0, stream>>>(
        b_xb, b_w1b, xt_b1, (float*)nullptr, b_t1b, 32768, 256, 32, 0.01f, 1);
    gemm_mfma_bt<<<dim3(256 / 128, 32768 / 128), blk, 0, stream>>>(
        b_t1b, b_w2b, xt_b2, b_res, b_resb, 32768, 256, 256, 0.f, 0);

    // ---- 5 GATv2 layers ----
    for (int L = 0; L < 5; L++) {
        const float* wl  = (const float*)d_in[7 + 4 * L];
        const float* wr  = (const float*)d_in[8 + 4 * L];
        const float* att = (const float*)d_in[9 + 4 * L];
        const float* gb  = (const float*)d_in[10 + 4 * L];
        int Fin = (L == 0) ? 512 : 1024;
        int HC  = (L == 4) ? 512 : 1024;
        const bf16* hin = (L == 0) ? b_resb : b_hb;

        transpose_f2b2<<<dim3(HC / 32, Fin / 32, 2), blk, 0, stream>>>(
            wl, b_wcat, wr, b_wcat + (size_t)HC * Fin, Fin, HC);
        gemm_mfma_dual<<<dim3(2 * HC / 128, NN / 128), blk, 0, stream>>>(
            hin, b_wcat, b_xlb, b_xrb, NN, 2 * HC, Fin, HC);
        if (L == 4) {
            gat_wave7<1><<<2048, dim3(128), 0, stream>>>(
                b_xlb, b_xrb, att, gb, i_rs, i_src,
                b_res, b_h, (bf16*)nullptr, f_sums);
        } else {
            gat_wave7<2><<<1024, blk, 0, stream>>>(
                b_xlb, b_xrb, att, gb, i_rs, i_src,
                (const float*)nullptr, (float*)nullptr, b_hb, (float*)nullptr);
        }
    }

    // ---- graph LN + softmax aggregation (single pass + combine) ----
    aggr_partial<<<dim3(BBG, 2, 8), blk, 0, stream>>>(
        b_h, f_sums, ln_w, ln_b, aggr_t, f_pm, f_pd, f_pa);
    aggr_combine<<<dim3(BBG, 2), blk, 0, stream>>>(f_pm, f_pd, f_pa, b_g);

    // ---- head MLP 512 -> 384 -> 256 -> 128 (fp32) ----
    gemm_f32<<<dim3(384 / 64, 1), blk, 0, stream>>>(
        b_g, m_w1, m_b1, b_m1, 64, 384, 512, 0.01f, 1);
    gemm_f32<<<dim3(256 / 64, 1), blk, 0, stream>>>(
        b_m1, m_w2, m_b2, b_m2, 64, 256, 384, 0.01f, 1);
    gemm_f32<<<dim3(128 / 64, 1), blk, 0, stream>>>(
        b_m2, m_w3, m_b3, out, 64, 128, 256, 0.f, 0);
}

// Round 7
// 1021.427 us; speedup vs baseline: 1.2118x; 1.0256x over previous
//
#include <hip/hip_runtime.h>
#include <hip/hip_bf16.h>

typedef __hip_bfloat16 bf16;

#define NN 16384          // gate nodes
#define BBG 64            // graphs
#define EE 49152          // directed edges (no self loops)
#define ET (EE + NN)      // edges + self loops = 65536
#define DD 512            // node feature dim (2F)
#define NG (NN / BBG)     // 256 nodes per graph

__device__ __forceinline__ float b2f(bf16 v) { return __bfloat162float(v); }
__device__ __forceinline__ bf16 f2b(float v) { return __float2bfloat16(v); }
__device__ __forceinline__ float sb2f(short s) {
    unsigned u = ((unsigned)(unsigned short)s) << 16;
    return __builtin_bit_cast(float, u);
}
__device__ __forceinline__ short f2bs(float v) {
    bf16 b = f2b(v);
    return __builtin_bit_cast(short, b);
}
__device__ __forceinline__ int clampi(int v, int lo, int hi)
{
    return v < lo ? lo : (v > hi ? hi : v);
}

typedef __attribute__((ext_vector_type(8))) short bf16x8;  // 8 bf16 = 4 VGPRs
typedef __attribute__((ext_vector_type(4))) float f32x4;

#define AS1 __attribute__((address_space(1)))
#define AS3 __attribute__((address_space(3)))

// ---------------------------------------------------------------------------
// MFMA bf16 GEMM (m97 structure, 128x128): kept for x_trans (K=32/256).
// ---------------------------------------------------------------------------
__global__ __launch_bounds__(256) void gemm_mfma_bt(
    const bf16* __restrict__ A, const bf16* __restrict__ Bt,
    const float* __restrict__ bias, float* __restrict__ C,
    bf16* __restrict__ Cb, int M, int N, int K, float slope, int has_act)
{
    __shared__ bf16 As[128 * 32];
    __shared__ bf16 Bs[128 * 32];
    const int tid = threadIdx.x;
    const int w = tid >> 6;
    const int l = tid & 63;
    const int bm = blockIdx.y * 128;
    const int bn = blockIdx.x * 128;
    const int wrow = (w >> 1) * 64;
    const int wcol = (w & 1) * 64;
    const int quad = l >> 4;
    const int c16 = l & 15;

    const int lrow = l >> 2;
    const int lchunk = l & 3;
    const bf16* Ag = A + (size_t)(bm + w * 16 + lrow) * K + lchunk * 8;
    const bf16* Bg = Bt + (size_t)(bn + w * 16 + lrow) * K + lchunk * 8;
    char* AsB = (char*)As;
    char* BsB = (char*)Bs;

    f32x4 acc[4][4] = {};

    for (int k0 = 0; k0 < K; k0 += 32) {
        __builtin_amdgcn_global_load_lds((const AS1 void*)(Ag + k0),
            (AS3 void*)(AsB + w * 1024), 16, 0, 0);
        __builtin_amdgcn_global_load_lds((const AS1 void*)(Ag + (size_t)64 * K + k0),
            (AS3 void*)(AsB + 4096 + w * 1024), 16, 0, 0);
        __builtin_amdgcn_global_load_lds((const AS1 void*)(Bg + k0),
            (AS3 void*)(BsB + w * 1024), 16, 0, 0);
        __builtin_amdgcn_global_load_lds((const AS1 void*)(Bg + (size_t)64 * K + k0),
            (AS3 void*)(BsB + 4096 + w * 1024), 16, 0, 0);
        __syncthreads();

        bf16x8 a[4], b[4];
#pragma unroll
        for (int i = 0; i < 4; i++) {
            int ra = wrow + i * 16 + c16;
            a[i] = *(const bf16x8*)(AsB + ra * 64 + quad * 16);
            int rb = wcol + i * 16 + c16;
            b[i] = *(const bf16x8*)(BsB + rb * 64 + quad * 16);
        }
#pragma unroll
        for (int i = 0; i < 4; i++)
#pragma unroll
            for (int j = 0; j < 4; j++)
                acc[i][j] = __builtin_amdgcn_mfma_f32_16x16x32_bf16(
                    a[i], b[j], acc[i][j], 0, 0, 0);
        __syncthreads();
    }

#pragma unroll
    for (int i = 0; i < 4; i++) {
#pragma unroll
        for (int j = 0; j < 4; j++) {
            int col = bn + wcol + j * 16 + c16;
            float bv = bias ? bias[col] : 0.f;
#pragma unroll
            for (int r = 0; r < 4; r++) {
                int row = bm + wrow + i * 16 + quad * 4 + r;
                float v = acc[i][j][r] + bv;
                if (has_act) v = (v >= 0.f) ? v : v * slope;
                if (C)  C[(size_t)row * N + col] = v;
                if (Cb) Cb[(size_t)row * N + col] = f2b(v);
            }
        }
    }
}

// ---------------------------------------------------------------------------
// gemm256_dual: 256x256 tile, BK=64, 8 waves (2Mx4N), 128KB LDS, counted
// vmcnt pipeline (T3/T4). The m97 128x128 2-barrier structure ceilings at
// ~36% because compute-per-stage (~80cy) << load latency; 256x256/BK=64
// gives ~2500cy of MFMA per k-tile and the counted s_waitcnt vmcnt(8)
// keeps the NEXT tile's 8 staging loads (per wave) in flight across the
// barrier - never draining to 0 mid-loop (m198: 1167 TF without swizzle
// vs 682 for the drain-to-0 version, m230).
// Schedule per k-tile: reads(lgkm implicit) -> barrier -> stage(t+2 into
// just-read buf) -> vmcnt(8) [t+1 landed; t+2 still flying] -> barrier.
// Bt = [wlT; wrT]: col<HC -> X0, else X1.
// ---------------------------------------------------------------------------
template<int KK>
__global__ __launch_bounds__(512, 1) void gemm256_dual(
    const bf16* __restrict__ A, const bf16* __restrict__ Bt,
    bf16* __restrict__ X0, bf16* __restrict__ X1, int HC)
{
    constexpr int NT = KK / 64;          // k-tiles
    __shared__ char smem[131072];        // A0|B0|A1|B1, 4 x 32KB
    char* const Abuf[2] = { smem,         smem + 65536 };
    char* const Bbuf[2] = { smem + 32768, smem + 98304 };
    const int tid = threadIdx.x;
    const int w = tid >> 6;              // 0..7
    const int l = tid & 63;
    const int wm = w >> 2;               // 0..1  (M half)
    const int wn = w & 3;                // 0..3  (N quarter)
    const int quad = l >> 4;
    const int c16 = l & 15;
    const int bm = blockIdx.y * 256;
    const int bn = blockIdx.x * 256;

    // staging: wave w owns rows [w*32, w*32+32) of A-tile and B-tile.
    // one global_load_lds = 64 lanes x 16B = 8 rows x 128B (lane -> row l>>3,
    // kchunk l&7); LDS dest wave-uniform base + lane*16 = linear row-major.
    const int srow = w * 32 + (l >> 3);
    const int schunk = (l & 7) * 8;
    const bf16* AgS = A + (size_t)(bm + srow) * KK + schunk;
    const bf16* BgS = Bt + (size_t)(bn + srow) * KK + schunk;
    const int lbase = (w * 32) * 128;

    auto stage = [&](int k0, int buf) {
#pragma unroll
        for (int op = 0; op < 4; ++op)
            __builtin_amdgcn_global_load_lds(
                (const AS1 void*)(AgS + (size_t)(op * 8) * KK + k0),
                (AS3 void*)(Abuf[buf] + lbase + op * 1024), 16, 0, 0);
#pragma unroll
        for (int op = 0; op < 4; ++op)
            __builtin_amdgcn_global_load_lds(
                (const AS1 void*)(BgS + (size_t)(op * 8) * KK + k0),
                (AS3 void*)(Bbuf[buf] + lbase + op * 1024), 16, 0, 0);
    };

    f32x4 acc[8][4] = {};

    auto tile_compute = [&](int buf) {
        bf16x8 bfrag[4][2];
#pragma unroll
        for (int j = 0; j < 4; ++j)
#pragma unroll
            for (int ks = 0; ks < 2; ++ks) {
                int rb = wn * 64 + j * 16 + c16;
                bfrag[j][ks] = *(const bf16x8*)(Bbuf[buf] + rb * 128 + ks * 64 + quad * 16);
            }
#pragma unroll
        for (int ip = 0; ip < 4; ++ip) {
            bf16x8 afrag[2][2];
#pragma unroll
            for (int ii = 0; ii < 2; ++ii)
#pragma unroll
                for (int ks = 0; ks < 2; ++ks) {
                    int ra = wm * 128 + (ip * 2 + ii) * 16 + c16;
                    afrag[ii][ks] = *(const bf16x8*)(Abuf[buf] + ra * 128 + ks * 64 + quad * 16);
                }
            __builtin_amdgcn_s_setprio(1);
#pragma unroll
            for (int ii = 0; ii < 2; ++ii)
#pragma unroll
                for (int j = 0; j < 4; ++j)
#pragma unroll
                    for (int ks = 0; ks < 2; ++ks)
                        acc[ip * 2 + ii][j] = __builtin_amdgcn_mfma_f32_16x16x32_bf16(
                            afrag[ii][ks], bfrag[j][ks], acc[ip * 2 + ii][j], 0, 0, 0);
            __builtin_amdgcn_s_setprio(0);
        }
    };

    // prologue: tiles 0,1 staged; wait only for tile 0 (tile 1 stays in flight)
    stage(0, 0);
    stage(64, 1);
    asm volatile("s_waitcnt vmcnt(8)" ::: "memory");
    __builtin_amdgcn_s_barrier();

#pragma unroll 1
    for (int tp = 0; tp < NT / 2; ++tp) {
        const int t0 = 2 * tp;
        // ---- even tile (buf0) ----
        tile_compute(0);
        __builtin_amdgcn_s_barrier();              // all reads of buf0 done
        if (t0 + 2 < NT) {
            stage((t0 + 2) * 64, 0);               // overwrite buf0 (safe now)
            asm volatile("s_waitcnt vmcnt(8)" ::: "memory");  // t0+1 landed
        } else {
            asm volatile("s_waitcnt vmcnt(0)" ::: "memory");
        }
        __builtin_amdgcn_s_barrier();              // publish across waves
        // ---- odd tile (buf1) ----
        tile_compute(1);
        __builtin_amdgcn_s_barrier();
        if (t0 + 3 < NT) {
            stage((t0 + 3) * 64, 1);
            asm volatile("s_waitcnt vmcnt(8)" ::: "memory");  // t0+2 landed
        } else {
            asm volatile("s_waitcnt vmcnt(0)" ::: "memory");
        }
        __builtin_amdgcn_s_barrier();
    }

#pragma unroll
    for (int i = 0; i < 8; ++i) {
#pragma unroll
        for (int j = 0; j < 4; ++j) {
            int col = bn + wn * 64 + j * 16 + c16;
            bf16* dst = (col < HC) ? (X0 + col) : (X1 + col - HC);
#pragma unroll
            for (int r = 0; r < 4; ++r) {
                int row = bm + wm * 128 + i * 16 + quad * 4 + r;
                dst[(size_t)row * HC] = f2b(acc[i][j][r]);
            }
        }
    }
}

// ---------------------------------------------------------------------------
// fp32 GEMM (head MLP only)
// ---------------------------------------------------------------------------
__global__ __launch_bounds__(256) void gemm_f32(
    const float* __restrict__ A, const float* __restrict__ W,
    const float* __restrict__ bias, float* __restrict__ C,
    int M, int N, int K, float slope, int has_act)
{
    const int BK = 16;
    __shared__ float Asm[BK][64 + 1];
    __shared__ float Wsm[BK][64 + 1];
    int tid = threadIdx.x;
    int bm = blockIdx.y * 64;
    int bn = blockIdx.x * 64;
    int tr = tid >> 4;
    int tc = tid & 15;
    float acc[4][4] = {};

    for (int k0 = 0; k0 < K; k0 += BK) {
        {
            int col = tid & 15;
            int row = tid >> 4;
#pragma unroll
            for (int p = 0; p < 4; p++) {
                int r = row + p * 16;
                Asm[col][r] = A[(size_t)(bm + r) * K + k0 + col];
            }
        }
        {
            int wc = tid & 63;
            int wr = tid >> 6;
#pragma unroll
            for (int p = 0; p < 4; p++) {
                int r = wr + p * 4;
                Wsm[r][wc] = W[(size_t)(k0 + r) * N + bn + wc];
            }
        }
        __syncthreads();
#pragma unroll
        for (int kk = 0; kk < BK; kk++) {
            float a[4], w[4];
#pragma unroll
            for (int i = 0; i < 4; i++) a[i] = Asm[kk][tr * 4 + i];
#pragma unroll
            for (int j = 0; j < 4; j++) w[j] = Wsm[kk][tc * 4 + j];
#pragma unroll
            for (int i = 0; i < 4; i++)
#pragma unroll
                for (int j = 0; j < 4; j++)
                    acc[i][j] += a[i] * w[j];
        }
        __syncthreads();
    }
#pragma unroll
    for (int i = 0; i < 4; i++) {
        int r = bm + tr * 4 + i;
#pragma unroll
        for (int j = 0; j < 4; j++) {
            int cn = bn + tc * 4 + j;
            float v = acc[i][j];
            if (bias) v += bias[cn];
            if (has_act) v = (v >= 0.f) ? v : v * slope;
            C[(size_t)r * N + cn] = v;
        }
    }
}

// ---------------------------------------------------------------------------
// Batched fp32 [R,C] -> bf16 [C,R] transpose-convert (z selects tensor pair)
// ---------------------------------------------------------------------------
__global__ __launch_bounds__(256) void transpose_f2b2(
    const float* __restrict__ in0, bf16* __restrict__ out0,
    const float* __restrict__ in1, bf16* __restrict__ out1, int R, int C)
{
    const float* in = blockIdx.z ? in1 : in0;
    bf16* out = blockIdx.z ? out1 : out0;
    __shared__ float tile[32][33];
    int c0 = blockIdx.x * 32;
    int r0 = blockIdx.y * 32;
    int tx = threadIdx.x & 31;
    int ty = threadIdx.x >> 5;
#pragma unroll
    for (int k = 0; k < 4; k++) {
        int r = ty + k * 8;
        tile[r][tx] = in[(size_t)(r0 + r) * C + c0 + tx];
    }
    __syncthreads();
#pragma unroll
    for (int k = 0; k < 4; k++) {
        int rr = ty + k * 8;
        out[(size_t)(c0 + rr) * R + r0 + tx] = f2b(tile[tx][rr]);
    }
}

__global__ void f2b_vec(const float* __restrict__ in, bf16* __restrict__ out, int n)
{
    int i = blockIdx.x * 256 + threadIdx.x;
    if (i < n) out[i] = f2b(in[i]);
}

// ---------------------------------------------------------------------------
// CSR build over dst (self loops: edge ids [EE, ET) are node e-EE)
// ---------------------------------------------------------------------------
__global__ void count_deg(const int* __restrict__ ei, int* __restrict__ deg)
{
    int e = blockIdx.x * 256 + threadIdx.x;
    if (e >= ET) return;
    int d = (e < EE) ? ei[EE + e] : (e - EE);
    d = clampi(d, 0, NN - 1);
    atomicAdd(&deg[d], 1);
}

__global__ __launch_bounds__(256) void scan_deg(const int* __restrict__ deg,
                                                int* __restrict__ rs)
{
    __shared__ int part[256];
    __shared__ int psum[257];
    int tid = threadIdx.x;
    const int per = NN / 256;
    int base = tid * per;
    int s = 0;
    for (int i = 0; i < per; i++) s += deg[base + i];
    part[tid] = s;
    __syncthreads();
    if (tid == 0) {
        int acc = 0;
        for (int i = 0; i < 256; i++) { psum[i] = acc; acc += part[i]; }
        psum[256] = acc;
    }
    __syncthreads();
    int acc = psum[tid];
    for (int i = 0; i < per; i++) { rs[base + i] = acc; acc += deg[base + i]; }
    if (tid == 0) rs[NN] = psum[256];
}

__global__ void fill_csr(const int* __restrict__ ei, const int* __restrict__ rs,
                         int* __restrict__ cur, int* __restrict__ csrc)
{
    int e = blockIdx.x * 256 + threadIdx.x;
    if (e >= ET) return;
    int s, d;
    if (e < EE) { s = ei[e]; d = ei[EE + e]; } else { s = d = e - EE; }
    s = clampi(s, 0, NN - 1);
    d = clampi(d, 0, NN - 1);
    int pos = atomicAdd(&cur[d], 1);
    int slot = clampi(rs[d] + pos, 0, ET - 1);
    csrc[slot] = s;
}

// ---------------------------------------------------------------------------
// GATv2 fused wave kernel, register pipeline (R4 gat_wave6). Used for L4
// (NH=1): R6 showed the LDS-staged variant cost occupancy (15.6%) and
// regressed L4 to 120us; this version ran sub-119.
// ---------------------------------------------------------------------------
template<int NH>
__global__ __launch_bounds__(256, 4) void gat_wave6(
    const bf16* __restrict__ xl, const bf16* __restrict__ xr,
    const float* __restrict__ att, const float* __restrict__ bias,
    const int* __restrict__ rs, const int* __restrict__ csrc,
    const float* __restrict__ res, float* __restrict__ out_f,
    bf16* __restrict__ out_b, float* __restrict__ lnsums)
{
    constexpr int HC = NH * 512;
    constexpr int PF = 6;
    constexpr int NODES = (NH == 2) ? 8 : 4;
    const int tid = threadIdx.x;
    const int w = tid >> 6;
    const int lane = tid & 63;
    const int wave_id = blockIdx.x * 4 + w;

    int msrc[NODES];
    int sdeg[NODES];
#pragma unroll
    for (int it = 0; it < NODES; ++it) {
        int gw = wave_id * NODES + it;
        int n = (NH == 2) ? (gw >> 1) : gw;
        int st = rs[n];
        int deg = clampi(rs[n + 1] - st, 1, 64);
        st = clampi(st, 0, ET - 1);
        st = __builtin_amdgcn_readfirstlane(st);
        deg = __builtin_amdgcn_readfirstlane(deg);
        sdeg[it] = deg;
        msrc[it] = csrc[st + ((lane < deg) ? lane : deg - 1)];
    }

    float av0[8], av1[8];
    {
        f32x4 t0 = *(const f32x4*)(att + lane * 8);
        f32x4 t1 = *(const f32x4*)(att + lane * 8 + 4);
#pragma unroll
        for (int k = 0; k < 4; k++) { av0[k] = t0[k]; av0[4 + k] = t1[k]; }
        if (NH == 2) {
            f32x4 t2 = *(const f32x4*)(att + 512 + lane * 8);
            f32x4 t3 = *(const f32x4*)(att + 512 + lane * 8 + 4);
#pragma unroll
            for (int k = 0; k < 4; k++) { av1[k] = t2[k]; av1[4 + k] = t3[k]; }
        } else {
#pragma unroll
            for (int k = 0; k < 8; k++) av1[k] = av0[k];
        }
    }

    f32x4 rows[2][PF];
    f32x4 rpx[2];

    auto issue = [&](int it, int pb) {
        int gw = wave_id * NODES + it;
        int n = (NH == 2) ? (gw >> 1) : gw;
        int h = (NH == 2) ? (gw & 1) : 0;
        int cb = h * 512 + lane * 8;
        rpx[pb] = *(const f32x4*)(xr + (size_t)n * HC + cb);
        int dm1 = sdeg[it] - 1;
#pragma unroll
        for (int r = 0; r < PF; r++) {
            int idx = (r < dm1) ? r : dm1;
            int s = __builtin_amdgcn_readlane(msrc[it], idx);
            s = clampi(s, 0, NN - 1);
            rows[pb][r] = *(const f32x4*)(xl + (size_t)s * HC + cb);
        }
    };

    auto compute = [&](int it, int pb) {
        int gw = wave_id * NODES + it;
        int n = (NH == 2) ? (gw >> 1) : gw;
        int h = (NH == 2) ? (gw & 1) : 0;
        int cb = h * 512 + lane * 8;
        int deg = sdeg[it];

        float rv[8], av[8];
        {
            bf16x8 xb = __builtin_bit_cast(bf16x8, rpx[pb]);
#pragma unroll
            for (int k = 0; k < 8; k++) {
                rv[k] = sb2f(xb[k]);
                av[k] = h ? av1[k] : av0[k];
            }
        }

        float part[PF];
#pragma unroll
        for (int r = 0; r < PF; r++) {
            bf16x8 rb = __builtin_bit_cast(bf16x8, rows[pb][r]);
            float p0 = 0.f, p1 = 0.f, p2 = 0.f, p3 = 0.f;
#pragma unroll
            for (int k = 0; k < 8; k += 4) {
                float x0 = sb2f(rb[k + 0]);
                float x1 = sb2f(rb[k + 1]);
                float x2 = sb2f(rb[k + 2]);
                float x3 = sb2f(rb[k + 3]);
                float u0 = x0 + rv[k + 0]; u0 = (u0 >= 0.f) ? u0 : 0.2f * u0;
                float u1 = x1 + rv[k + 1]; u1 = (u1 >= 0.f) ? u1 : 0.2f * u1;
                float u2 = x2 + rv[k + 2]; u2 = (u2 >= 0.f) ? u2 : 0.2f * u2;
                float u3 = x3 + rv[k + 3]; u3 = (u3 >= 0.f) ? u3 : 0.2f * u3;
                p0 = fmaf(av[k + 0], u0, p0);
                p1 = fmaf(av[k + 1], u1, p1);
                p2 = fmaf(av[k + 2], u2, p2);
                p3 = fmaf(av[k + 3], u3, p3);
            }
            part[r] = (p0 + p1) + (p2 + p3);
        }

#pragma unroll
        for (int msk = 32; msk; msk >>= 1) {
#pragma unroll
            for (int r = 0; r < PF; r++) part[r] += __shfl_xor(part[r], msk);
        }

        float m = -1e30f;
#pragma unroll
        for (int r = 0; r < PF; r++) {
            float vr = (r < deg) ? part[r] : -1e30f;
            m = fmaxf(m, vr);
        }
        float den = 0.f;
        float pw[PF];
#pragma unroll
        for (int r = 0; r < PF; r++) {
            float e = __expf(part[r] - m);
            pw[r] = (r < deg) ? e : 0.f;
            den += pw[r];
        }

        float acc[8];
#pragma unroll
        for (int k = 0; k < 8; k++) acc[k] = 0.f;
#pragma unroll
        for (int r = 0; r < PF; r++) {
            bf16x8 rb = __builtin_bit_cast(bf16x8, rows[pb][r]);
#pragma unroll
            for (int k = 0; k < 8; k++)
                acc[k] = fmaf(pw[r], sb2f(rb[k]), acc[k]);
        }

        if (deg > PF) {
            for (int i = PF; i < deg; i++) {
                int s = __builtin_amdgcn_readlane(msrc[it], i);
                s = clampi(s, 0, NN - 1);
                f32x4 rw = *(const f32x4*)(xl + (size_t)s * HC + cb);
                bf16x8 rb = __builtin_bit_cast(bf16x8, rw);
                float pt = 0.f;
#pragma unroll
                for (int k = 0; k < 8; k++) {
                    float x = sb2f(rb[k]);
                    float u = x + rv[k];
                    u = (u >= 0.f) ? u : 0.2f * u;
                    pt = fmaf(av[k], u, pt);
                }
#pragma unroll
                for (int msk = 32; msk; msk >>= 1) pt += __shfl_xor(pt, msk);
                float mn = fmaxf(m, pt);
                float rr = __expf(m - mn);
                float pi = __expf(pt - mn);
                m = mn;
                den = den * rr + pi;
#pragma unroll
                for (int k = 0; k < 8; k++) {
                    float x = sb2f(rb[k]);
                    acc[k] = fmaf(acc[k], rr, pi * x);
                }
            }
        }

        float inv = 1.f / den;
        f32x4 b0 = *(const f32x4*)(bias + cb);
        f32x4 b1 = *(const f32x4*)(bias + cb + 4);
        float vals[8];
#pragma unroll
        for (int k = 0; k < 8; k++) {
            float bv = (k < 4) ? b0[k] : b1[k - 4];
            float v = fmaf(acc[k], inv, bv);
            v = (v >= 0.f) ? v : 0.01f * v;
            vals[k] = v;
        }
        if (res) {
            float ls = 0.f, ls2 = 0.f;
#pragma unroll
            for (int k = 0; k < 8; k++) {
                vals[k] += res[(size_t)n * HC + cb + k];
                ls += vals[k];
                ls2 += vals[k] * vals[k];
            }
#pragma unroll
            for (int v = 0; v < 2; v++) {
                f32x4 ov;
#pragma unroll
                for (int k = 0; k < 4; k++) ov[k] = vals[v * 4 + k];
                *(f32x4*)(out_f + (size_t)n * HC + cb + v * 4) = ov;
            }
            if (lnsums) {
#pragma unroll
                for (int msk = 32; msk; msk >>= 1) {
                    ls += __shfl_xor(ls, msk);
                    ls2 += __shfl_xor(ls2, msk);
                }
                if (lane == 0) {
                    int g = n >> 8;
                    atomicAdd(&lnsums[g], ls);
                    atomicAdd(&lnsums[BBG + g], ls2);
                }
            }
        } else {
            bf16x8 ov;
#pragma unroll
            for (int k = 0; k < 8; k++) ov[k] = f2bs(vals[k]);
            *(bf16x8*)(out_b + (size_t)n * HC + cb) = ov;
        }
    };

    issue(0, 0);
#pragma unroll
    for (int it = 0; it < NODES; ++it) {
        int pb = it & 1;
        if (it + 1 < NODES) issue(it + 1, pb ^ 1);
        compute(it, pb);
    }
}

// ---------------------------------------------------------------------------
// GATv2 edge phase, LDS-staged async pipeline with counted vmcnt (R6).
// Kept for NH=2 (it improved those layers); L4 uses gat_wave6.
// ---------------------------------------------------------------------------
template<int NH>
__global__ __launch_bounds__(256) void gat_wave7(
    const bf16* __restrict__ xl, const bf16* __restrict__ xr,
    const float* __restrict__ att, const float* __restrict__ bias,
    const int* __restrict__ rs, const int* __restrict__ csrc,
    const float* __restrict__ res, float* __restrict__ out_f,
    bf16* __restrict__ out_b, float* __restrict__ lnsums)
{
    constexpr int HC = NH * 512;
    constexpr int PF = 6;
    constexpr int NODES = (NH == 2) ? 8 : 4;
    constexpr int WPB = 4;
    constexpr int SLOTS = 7;
    __shared__ char smem[WPB * 2 * SLOTS * 1024];

    const int tid = threadIdx.x;
    const int w = tid >> 6;
    const int lane = tid & 63;
    const int wave_id = blockIdx.x * WPB + w;

    int msrc[NODES];
    int sdeg[NODES];
#pragma unroll
    for (int it = 0; it < NODES; ++it) {
        int gw = wave_id * NODES + it;
        int n = (NH == 2) ? (gw >> 1) : gw;
        int st = rs[n];
        int deg = clampi(rs[n + 1] - st, 1, 64);
        st = clampi(st, 0, ET - 1);
        st = __builtin_amdgcn_readfirstlane(st);
        deg = __builtin_amdgcn_readfirstlane(deg);
        sdeg[it] = deg;
        msrc[it] = csrc[st + ((lane < deg) ? lane : deg - 1)];
    }

    float av0[8], av1[8], bv0[8], bv1[8];
    {
        f32x4 t0 = *(const f32x4*)(att + lane * 8);
        f32x4 t1 = *(const f32x4*)(att + lane * 8 + 4);
        f32x4 u0 = *(const f32x4*)(bias + lane * 8);
        f32x4 u1 = *(const f32x4*)(bias + lane * 8 + 4);
#pragma unroll
        for (int k = 0; k < 4; k++) {
            av0[k] = t0[k]; av0[4 + k] = t1[k];
            bv0[k] = u0[k]; bv0[4 + k] = u1[k];
        }
        if (NH == 2) {
            f32x4 t2 = *(const f32x4*)(att + 512 + lane * 8);
            f32x4 t3 = *(const f32x4*)(att + 512 + lane * 8 + 4);
            f32x4 u2 = *(const f32x4*)(bias + 512 + lane * 8);
            f32x4 u3 = *(const f32x4*)(bias + 512 + lane * 8 + 4);
#pragma unroll
            for (int k = 0; k < 4; k++) {
                av1[k] = t2[k]; av1[4 + k] = t3[k];
                bv1[k] = u2[k]; bv1[4 + k] = u3[k];
            }
        } else {
#pragma unroll
            for (int k = 0; k < 8; k++) { av1[k] = av0[k]; bv1[k] = bv0[k]; }
        }
    }

    auto issue = [&](int it, int pb) {
        int gw = wave_id * NODES + it;
        int n = (NH == 2) ? (gw >> 1) : gw;
        int h = (NH == 2) ? (gw & 1) : 0;
        char* buf = smem + (size_t)((w * 2 + pb) * SLOTS) * 1024;
        const bf16* xrrow = xr + (size_t)n * HC + h * 512 + lane * 8;
        __builtin_amdgcn_global_load_lds((const AS1 void*)xrrow,
            (AS3 void*)buf, 16, 0, 0);
        int dm1 = sdeg[it] - 1;
#pragma unroll
        for (int r = 0; r < PF; r++) {
            int idx = (r < dm1) ? r : dm1;
            int s = __builtin_amdgcn_readlane(msrc[it], idx);
            s = clampi(s, 0, NN - 1);
            const bf16* row = xl + (size_t)s * HC + h * 512 + lane * 8;
            __builtin_amdgcn_global_load_lds((const AS1 void*)row,
                (AS3 void*)(buf + (1 + r) * 1024), 16, 0, 0);
        }
    };

    auto compute = [&](int it, int pb) {
        int gw = wave_id * NODES + it;
        int n = (NH == 2) ? (gw >> 1) : gw;
        int h = (NH == 2) ? (gw & 1) : 0;
        int cb = h * 512 + lane * 8;
        int deg = sdeg[it];
        char* buf = smem + (size_t)((w * 2 + pb) * SLOTS) * 1024;

        float rv[8], av[8];
        {
            bf16x8 xb = *(const bf16x8*)(buf + lane * 16);
#pragma unroll
            for (int k = 0; k < 8; k++) {
                rv[k] = sb2f(xb[k]);
                av[k] = h ? av1[k] : av0[k];
            }
        }
        bf16x8 rloc[PF];
#pragma unroll
        for (int r = 0; r < PF; r++)
            rloc[r] = *(const bf16x8*)(buf + (1 + r) * 1024 + lane * 16);

        float part[PF];
#pragma unroll
        for (int r = 0; r < PF; r++) {
            float p0 = 0.f, p1 = 0.f, p2 = 0.f, p3 = 0.f;
#pragma unroll
            for (int k = 0; k < 8; k += 4) {
                float x0 = sb2f(rloc[r][k + 0]);
                float x1 = sb2f(rloc[r][k + 1]);
                float x2 = sb2f(rloc[r][k + 2]);
                float x3 = sb2f(rloc[r][k + 3]);
                float u0 = x0 + rv[k + 0]; u0 = (u0 >= 0.f) ? u0 : 0.2f * u0;
                float u1 = x1 + rv[k + 1]; u1 = (u1 >= 0.f) ? u1 : 0.2f * u1;
                float u2 = x2 + rv[k + 2]; u2 = (u2 >= 0.f) ? u2 : 0.2f * u2;
                float u3 = x3 + rv[k + 3]; u3 = (u3 >= 0.f) ? u3 : 0.2f * u3;
                p0 = fmaf(av[k + 0], u0, p0);
                p1 = fmaf(av[k + 1], u1, p1);
                p2 = fmaf(av[k + 2], u2, p2);
                p3 = fmaf(av[k + 3], u3, p3);
            }
            part[r] = (p0 + p1) + (p2 + p3);
        }

#pragma unroll
        for (int msk = 32; msk; msk >>= 1) {
#pragma unroll
            for (int r = 0; r < PF; r++) part[r] += __shfl_xor(part[r], msk);
        }

        float m = -1e30f;
#pragma unroll
        for (int r = 0; r < PF; r++) {
            float vr = (r < deg) ? part[r] : -1e30f;
            m = fmaxf(m, vr);
        }
        float den = 0.f;
        float pw[PF];
#pragma unroll
        for (int r = 0; r < PF; r++) {
            float e = __expf(part[r] - m);
            pw[r] = (r < deg) ? e : 0.f;
            den += pw[r];
        }

        float acc[8];
#pragma unroll
        for (int k = 0; k < 8; k++) acc[k] = 0.f;
#pragma unroll
        for (int r = 0; r < PF; r++) {
#pragma unroll
            for (int k = 0; k < 8; k++)
                acc[k] = fmaf(pw[r], sb2f(rloc[r][k]), acc[k]);
        }

        if (deg > PF) {
            for (int i = PF; i < deg; i++) {
                int s = __builtin_amdgcn_readlane(msrc[it], i);
                s = clampi(s, 0, NN - 1);
                f32x4 rw = *(const f32x4*)(xl + (size_t)s * HC + cb);
                bf16x8 rb = __builtin_bit_cast(bf16x8, rw);
                float pt = 0.f;
#pragma unroll
                for (int k = 0; k < 8; k++) {
                    float x = sb2f(rb[k]);
                    float u = x + rv[k];
                    u = (u >= 0.f) ? u : 0.2f * u;
                    pt = fmaf(av[k], u, pt);
                }
#pragma unroll
                for (int msk = 32; msk; msk >>= 1) pt += __shfl_xor(pt, msk);
                float mn = fmaxf(m, pt);
                float rr = __expf(m - mn);
                float pi = __expf(pt - mn);
                m = mn;
                den = den * rr + pi;
#pragma unroll
                for (int k = 0; k < 8; k++) {
                    float x = sb2f(rb[k]);
                    acc[k] = fmaf(acc[k], rr, pi * x);
                }
            }
        }

        float inv = 1.f / den;
        float vals[8];
#pragma unroll
        for (int k = 0; k < 8; k++) {
            float bv = h ? bv1[k] : bv0[k];
            float v = fmaf(acc[k], inv, bv);
            v = (v >= 0.f) ? v : 0.01f * v;
            vals[k] = v;
        }
        bf16x8 ov;
#pragma unroll
        for (int k = 0; k < 8; k++) ov[k] = f2bs(vals[k]);
        *(bf16x8*)(out_b + (size_t)n * HC + cb) = ov;
    };

    issue(0, 0);
#pragma unroll
    for (int it = 0; it < NODES; ++it) {
        int pb = it & 1;
        if (it + 1 < NODES) {
            issue(it + 1, pb ^ 1);
            asm volatile("s_waitcnt vmcnt(7)" ::: "memory");
        } else {
            asm volatile("s_waitcnt vmcnt(0)" ::: "memory");
        }
        __builtin_amdgcn_sched_barrier(0);
        compute(it, pb);
    }
}

// ---------------------------------------------------------------------------
// LN apply + channel-wise online-softmax aggregation, node-chunked partials.
// ---------------------------------------------------------------------------
__global__ __launch_bounds__(256) void aggr_partial(
    const float* __restrict__ h, const float* __restrict__ lnsums,
    const float* __restrict__ lnw, const float* __restrict__ lnb,
    const float* __restrict__ t_, float* __restrict__ pm,
    float* __restrict__ pd, float* __restrict__ pa)
{
    int g = blockIdx.x, ch = blockIdx.y, nk = blockIdx.z;
    int tid = threadIdx.x;
    int c = ch * 256 + tid;
    const float tot = (float)(NG * DD);
    float S = lnsums[g], S2 = lnsums[BBG + g];
    float mu = S / tot;
    float iv = rsqrtf(fmaxf(S2 / tot - mu * mu, 0.f) + 1e-5f);
    float w = lnw[c], b = lnb[c], t = t_[0];
    size_t base = (size_t)g * NG * DD + (size_t)nk * 32 * DD + c;
    float m = -1e30f, den = 0.f, acc = 0.f;
    for (int i = 0; i < 32; i++) {
        float hn = (h[base + (size_t)i * DD] - mu) * iv * w + b;
        float lg = hn * t;
        if (lg > m) {
            float r = __expf(m - lg);
            den *= r; acc *= r; m = lg;
        }
        float p = __expf(lg - m);
        den += p; acc += p * hn;
    }
    size_t idx = (((size_t)g * 2 + ch) * 8 + nk) * 256 + tid;
    pm[idx] = m; pd[idx] = den; pa[idx] = acc;
}

__global__ __launch_bounds__(256) void aggr_combine(
    const float* __restrict__ pm, const float* __restrict__ pd,
    const float* __restrict__ pa, float* __restrict__ gout)
{
    int g = blockIdx.x, ch = blockIdx.y;
    int tid = threadIdx.x;
    size_t base = (((size_t)g * 2 + ch) * 8) * 256 + tid;
    float m = -1e30f;
#pragma unroll
    for (int k = 0; k < 8; k++) m = fmaxf(m, pm[base + k * 256]);
    float den = 0.f, acc = 0.f;
#pragma unroll
    for (int k = 0; k < 8; k++) {
        float r = __expf(pm[base + k * 256] - m);
        den += pd[base + k * 256] * r;
        acc += pa[base + k * 256] * r;
    }
    gout[(size_t)g * DD + ch * 256 + tid] = acc / den;
}

// ---------------------------------------------------------------------------
extern "C" void kernel_launch(void* const* d_in, const int* in_sizes, int n_in,
                              void* d_out, int out_size, void* d_ws, size_t ws_size,
                              hipStream_t stream)
{
    const float* x      = (const float*)d_in[0];
    const int*   ei     = (const int*)d_in[1];
    const float* xt_w1  = (const float*)d_in[3];
    const float* xt_b1  = (const float*)d_in[4];
    const float* xt_w2  = (const float*)d_in[5];
    const float* xt_b2  = (const float*)d_in[6];
    const float* ln_w   = (const float*)d_in[27];
    const float* ln_b   = (const float*)d_in[28];
    const float* aggr_t = (const float*)d_in[29];
    const float* m_w1   = (const float*)d_in[30];
    const float* m_b1   = (const float*)d_in[31];
    const float* m_w2   = (const float*)d_in[32];
    const float* m_b2   = (const float*)d_in[33];
    const float* m_w3   = (const float*)d_in[34];
    const float* m_b3   = (const float*)d_in[35];
    float* out = (float*)d_out;

    // ---- workspace layout (256B aligned); ints first ----
    char* p = (char*)d_ws;
    auto take = [&](size_t bytes) {
        char* r = p;
        p += (bytes + 255) & ~(size_t)255;
        return r;
    };
    int* i_deg     = (int*)take((size_t)(NN + 1) * 4);
    int* i_rs      = (int*)take((size_t)(NN + 1) * 4);
    int* i_cur     = (int*)take((size_t)NN * 4);
    int* i_src     = (int*)take((size_t)ET * 4);
    float* f_sums  = (float*)take((size_t)2 * BBG * 4);
    float* f_pm    = (float*)take((size_t)BBG * 2 * 8 * 256 * 4);
    float* f_pd    = (float*)take((size_t)BBG * 2 * 8 * 256 * 4);
    float* f_pa    = (float*)take((size_t)BBG * 2 * 8 * 256 * 4);
    float* b_g     = (float*)take((size_t)BBG * DD * 4);
    float* b_m1    = (float*)take((size_t)BBG * 384 * 4);
    float* b_m2    = (float*)take((size_t)BBG * 256 * 4);
    float* b_res   = (float*)take((size_t)NN * DD * 4);
    float* b_h     = (float*)take((size_t)NN * DD * 4);
    bf16* b_resb   = (bf16*)take((size_t)NN * DD * 2);
    bf16* b_hb     = (bf16*)take((size_t)NN * 1024 * 2);
    bf16* b_xlb    = (bf16*)take((size_t)NN * 1024 * 2);
    bf16* b_xrb    = (bf16*)take((size_t)NN * 1024 * 2);
    bf16* b_xb     = (bf16*)take((size_t)2 * NN * 32 * 2);
    bf16* b_wcat   = (bf16*)take((size_t)2048 * 1024 * 2);  // [wlT; wrT]
    bf16* b_w1b    = (bf16*)take((size_t)32 * 256 * 2);
    bf16* b_w2b    = (bf16*)take((size_t)256 * 256 * 2);
    bf16* b_t1b = b_hb;

    dim3 blk(256);

    // ---- CSR build + LN-sum zero ----
    hipMemsetAsync(i_deg, 0, (size_t)(NN + 1) * 4, stream);
    hipMemsetAsync(i_cur, 0, (size_t)NN * 4, stream);
    hipMemsetAsync(f_sums, 0, (size_t)2 * BBG * 4, stream);
    count_deg<<<ET / 256, blk, 0, stream>>>(ei, i_deg);
    scan_deg<<<1, blk, 0, stream>>>(i_deg, i_rs);
    fill_csr<<<ET / 256, blk, 0, stream>>>(ei, i_rs, i_cur, i_src);

    // ---- weight converts for x_trans + x convert ----
    f2b_vec<<<(2 * NN * 32 + 255) / 256, blk, 0, stream>>>(x, b_xb, 2 * NN * 32);
    transpose_f2b2<<<dim3(256 / 32, 32 / 32, 1), blk, 0, stream>>>(
        xt_w1, b_w1b, xt_w1, b_w1b, 32, 256);
    transpose_f2b2<<<dim3(256 / 32, 256 / 32, 1), blk, 0, stream>>>(
        xt_w2, b_w2b, xt_w2, b_w2b, 256, 256);

    // ---- x_trans ----
    gemm_mfma_bt<<<dim3(256 / 128, 32768 / 128), blk, 0, stream>>>(
        b_xb, b_w1b, xt_b1, (float*)nullptr, b_t1b, 32768, 256, 32, 0.01f, 1);
    gemm_mfma_bt<<<dim3(256 / 128, 32768 / 128), blk, 0, stream>>>(
        b_t1b, b_w2b, xt_b2, b_res, b_resb, 32768, 256, 256, 0.f, 0);

    // ---- 5 GATv2 layers ----
    for (int L = 0; L < 5; L++) {
        const float* wl  = (const float*)d_in[7 + 4 * L];
        const float* wr  = (const float*)d_in[8 + 4 * L];
        const float* att = (const float*)d_in[9 + 4 * L];
        const float* gb  = (const float*)d_in[10 + 4 * L];
        int Fin = (L == 0) ? 512 : 1024;
        int HC  = (L == 4) ? 512 : 1024;
        const bf16* hin = (L == 0) ? b_resb : b_hb;

        transpose_f2b2<<<dim3(HC / 32, Fin / 32, 2), blk, 0, stream>>>(
            wl, b_wcat, wr, b_wcat + (size_t)HC * Fin, Fin, HC);
        if (L == 0)
            gemm256_dual<512><<<dim3(2048 / 256, NN / 256), dim3(512), 0, stream>>>(
                hin, b_wcat, b_xlb, b_xrb, 1024);
        else if (L == 4)
            gemm256_dual<1024><<<dim3(1024 / 256, NN / 256), dim3(512), 0, stream>>>(
                hin, b_wcat, b_xlb, b_xrb, 512);
        else
            gemm256_dual<1024><<<dim3(2048 / 256, NN / 256), dim3(512), 0, stream>>>(
                hin, b_wcat, b_xlb, b_xrb, 1024);

        if (L == 4) {
            gat_wave6<1><<<1024, blk, 0, stream>>>(
                b_xlb, b_xrb, att, gb, i_rs, i_src,
                b_res, b_h, (bf16*)nullptr, f_sums);
        } else {
            gat_wave7<2><<<1024, blk, 0, stream>>>(
                b_xlb, b_xrb, att, gb, i_rs, i_src,
                (const float*)nullptr, (float*)nullptr, b_hb, (float*)nullptr);
        }
    }

    // ---- graph LN + softmax aggregation (single pass + combine) ----
    aggr_partial<<<dim3(BBG, 2, 8), blk, 0, stream>>>(
        b_h, f_sums, ln_w, ln_b, aggr_t, f_pm, f_pd, f_pa);
    aggr_combine<<<dim3(BBG, 2), blk, 0, stream>>>(f_pm, f_pd, f_pa, b_g);

    // ---- head MLP 512 -> 384 -> 256 -> 128 (fp32) ----
    gemm_f32<<<dim3(384 / 64, 1), blk, 0, stream>>>(
        b_g, m_w1, m_b1, b_m1, 64, 384, 512, 0.01f, 1);
    gemm_f32<<<dim3(256 / 64, 1), blk, 0, stream>>>(
        b_m1, m_w2, m_b2, b_m2, 64, 256, 384, 0.01f, 1);
    gemm_f32<<<dim3(128 / 64, 1), blk, 0, stream>>>(
        b_m2, m_w3, m_b3, out, 64, 128, 256, 0.f, 0);
}

// Round 8
// 956.828 us; speedup vs baseline: 1.2936x; 1.0675x over previous
//
#include <hip/hip_runtime.h>
#include <hip/hip_bf16.h>

typedef __hip_bfloat16 bf16;

#define NN 16384          // gate nodes
#define BBG 64            // graphs
#define EE 49152          // directed edges (no self loops)
#define ET (EE + NN)      // edges + self loops = 65536
#define DD 512            // node feature dim (2F)
#define NG (NN / BBG)     // 256 nodes per graph

__device__ __forceinline__ float b2f(bf16 v) { return __bfloat162float(v); }
__device__ __forceinline__ bf16 f2b(float v) { return __float2bfloat16(v); }
__device__ __forceinline__ float sb2f(short s) {
    unsigned u = ((unsigned)(unsigned short)s) << 16;
    return __builtin_bit_cast(float, u);
}
__device__ __forceinline__ short f2bs(float v) {
    bf16 b = f2b(v);
    return __builtin_bit_cast(short, b);
}
__device__ __forceinline__ int clampi(int v, int lo, int hi)
{
    return v < lo ? lo : (v > hi ? hi : v);
}

typedef __attribute__((ext_vector_type(8))) short bf16x8;  // 8 bf16 = 4 VGPRs
typedef __attribute__((ext_vector_type(4))) float f32x4;

#define AS1 __attribute__((address_space(1)))
#define AS3 __attribute__((address_space(3)))

// ---------------------------------------------------------------------------
// MFMA bf16 GEMM (m97 structure, 128x128): kept for x_trans (K=32/256).
// ---------------------------------------------------------------------------
__global__ __launch_bounds__(256) void gemm_mfma_bt(
    const bf16* __restrict__ A, const bf16* __restrict__ Bt,
    const float* __restrict__ bias, float* __restrict__ C,
    bf16* __restrict__ Cb, int M, int N, int K, float slope, int has_act)
{
    __shared__ bf16 As[128 * 32];
    __shared__ bf16 Bs[128 * 32];
    const int tid = threadIdx.x;
    const int w = tid >> 6;
    const int l = tid & 63;
    const int bm = blockIdx.y * 128;
    const int bn = blockIdx.x * 128;
    const int wrow = (w >> 1) * 64;
    const int wcol = (w & 1) * 64;
    const int quad = l >> 4;
    const int c16 = l & 15;

    const int lrow = l >> 2;
    const int lchunk = l & 3;
    const bf16* Ag = A + (size_t)(bm + w * 16 + lrow) * K + lchunk * 8;
    const bf16* Bg = Bt + (size_t)(bn + w * 16 + lrow) * K + lchunk * 8;
    char* AsB = (char*)As;
    char* BsB = (char*)Bs;

    f32x4 acc[4][4] = {};

    for (int k0 = 0; k0 < K; k0 += 32) {
        __builtin_amdgcn_global_load_lds((const AS1 void*)(Ag + k0),
            (AS3 void*)(AsB + w * 1024), 16, 0, 0);
        __builtin_amdgcn_global_load_lds((const AS1 void*)(Ag + (size_t)64 * K + k0),
            (AS3 void*)(AsB + 4096 + w * 1024), 16, 0, 0);
        __builtin_amdgcn_global_load_lds((const AS1 void*)(Bg + k0),
            (AS3 void*)(BsB + w * 1024), 16, 0, 0);
        __builtin_amdgcn_global_load_lds((const AS1 void*)(Bg + (size_t)64 * K + k0),
            (AS3 void*)(BsB + 4096 + w * 1024), 16, 0, 0);
        __syncthreads();

        bf16x8 a[4], b[4];
#pragma unroll
        for (int i = 0; i < 4; i++) {
            int ra = wrow + i * 16 + c16;
            a[i] = *(const bf16x8*)(AsB + ra * 64 + quad * 16);
            int rb = wcol + i * 16 + c16;
            b[i] = *(const bf16x8*)(BsB + rb * 64 + quad * 16);
        }
#pragma unroll
        for (int i = 0; i < 4; i++)
#pragma unroll
            for (int j = 0; j < 4; j++)
                acc[i][j] = __builtin_amdgcn_mfma_f32_16x16x32_bf16(
                    a[i], b[j], acc[i][j], 0, 0, 0);
        __syncthreads();
    }

#pragma unroll
    for (int i = 0; i < 4; i++) {
#pragma unroll
        for (int j = 0; j < 4; j++) {
            int col = bn + wcol + j * 16 + c16;
            float bv = bias ? bias[col] : 0.f;
#pragma unroll
            for (int r = 0; r < 4; r++) {
                int row = bm + wrow + i * 16 + quad * 4 + r;
                float v = acc[i][j][r] + bv;
                if (has_act) v = (v >= 0.f) ? v : v * slope;
                if (C)  C[(size_t)row * N + col] = v;
                if (Cb) Cb[(size_t)row * N + col] = f2b(v);
            }
        }
    }
}

// ---------------------------------------------------------------------------
// gemm256_8ph: full 8-phase 256x256 dual GEMM (T3+T4+T5, m198/m201 template).
// BK=64 split into two k-halves of 32. LDS 128KB: A[db][kh] 4x16KB + B same.
// Per phase: 8 ds_read_b128 (one rows-half x one k-half) -> 16 MFMA
// (setprio). Stages (A+B of one k-half = 4 gll/wave) at ODD phases;
// s_waitcnt vmcnt(8) at EVEN phases (2 stage-events may fly; never 0
// mid-loop). Ledger (verified): stage@p targets region last read at p-2;
// each staged half is >=3 events old at the vmcnt preceding its first read.
//   ph1:(b0,rh0,k0)+stage(t+1,k1->b1)   ph2:(b0,rh1,k0)+vm
//   ph3:(b0,rh0,k1)+stage(t+2,k0->b0)   ph4:(b0,rh1,k1)+vm
//   ph5:(b1,rh0,k0)+stage(t+2,k1->b0)   ph6:(b1,rh1,k0)+vm
//   ph7:(b1,rh0,k1)+stage(t+3,k0->b1)   ph8:(b1,rh1,k1)+vm
// Prologue: stage t0k0,t0k1,t1k0; vmcnt(8); barrier. Tail stages clamp to
// NT-1 (dead regions, never read). Per-wave reads drained (lgkmcnt(0)+
// sched_barrier) before the single trailing barrier of each phase.
// ---------------------------------------------------------------------------
template<int KK>
__global__ __launch_bounds__(512, 2) void gemm256_8ph(
    const bf16* __restrict__ A, const bf16* __restrict__ Bt,
    bf16* __restrict__ X0, bf16* __restrict__ X1, int HC)
{
    constexpr int NT = KK / 64;          // 64-wide K-tiles (even)
    __shared__ char smem[131072];
    const int tid = threadIdx.x;
    const int w = tid >> 6;              // 0..7
    const int l = tid & 63;
    const int wm = w >> 2;               // 0..1 (M half: 128 rows)
    const int wn = w & 3;                // 0..3 (N quarter: 64 cols)
    const int quad = l >> 4;
    const int c16 = l & 15;
    const int bm = blockIdx.y * 256;
    const int bn = blockIdx.x * 256;

    // staging: wave w owns panel rows [w*32, w*32+32); one gll = 16 rows x
    // 64B (lane -> row l>>2, 16B-chunk l&3); LDS dest linear row-major.
    const int r_loc = l >> 2;
    const int qc = l & 3;
    const int srow = w * 32;
    const bf16* Ag = A + (size_t)(bm + srow + r_loc) * KK + qc * 8;
    const bf16* Bg = Bt + (size_t)(bn + srow + r_loc) * KK + qc * 8;

    auto stage = [&](int t, int kh, int db) {
        const int koff = t * 64 + kh * 32;
        char* ab = smem + (db * 2 + kh) * 16384 + srow * 64;
        char* bb = ab + 65536;
#pragma unroll
        for (int win = 0; win < 2; ++win)
            __builtin_amdgcn_global_load_lds(
                (const AS1 void*)(Ag + (size_t)(win * 16) * KK + koff),
                (AS3 void*)(ab + win * 1024), 16, 0, 0);
#pragma unroll
        for (int win = 0; win < 2; ++win)
            __builtin_amdgcn_global_load_lds(
                (const AS1 void*)(Bg + (size_t)(win * 16) * KK + koff),
                (AS3 void*)(bb + win * 1024), 16, 0, 0);
    };

    f32x4 acc[8][4] = {};

    auto phase = [&](int db, int rh, int kh,
                     int st_t, int st_kh, int st_db, bool do_stage, bool do_vm) {
        const char* Ab = smem + (db * 2 + kh) * 16384;
        const char* Bb = Ab + 65536;
        bf16x8 af[4], bfr[4];
#pragma unroll
        for (int rt = 0; rt < 4; ++rt) {
            int row = wm * 128 + rh * 64 + rt * 16 + c16;
            af[rt] = *(const bf16x8*)(Ab + row * 64 + quad * 16);
        }
#pragma unroll
        for (int ct = 0; ct < 4; ++ct) {
            int row = wn * 64 + ct * 16 + c16;
            bfr[ct] = *(const bf16x8*)(Bb + row * 64 + quad * 16);
        }
        if (do_stage) stage(st_t, st_kh, st_db);
        __builtin_amdgcn_s_setprio(1);
#pragma unroll
        for (int rt = 0; rt < 4; ++rt)
#pragma unroll
            for (int ct = 0; ct < 4; ++ct)
                acc[rh * 4 + rt][ct] = __builtin_amdgcn_mfma_f32_16x16x32_bf16(
                    af[rt], bfr[ct], acc[rh * 4 + rt][ct], 0, 0, 0);
        __builtin_amdgcn_s_setprio(0);
        if (do_vm) asm volatile("s_waitcnt vmcnt(8) lgkmcnt(0)" ::: "memory");
        else       asm volatile("s_waitcnt lgkmcnt(0)" ::: "memory");
        __builtin_amdgcn_sched_barrier(0);
        __builtin_amdgcn_s_barrier();
    };

    // ---- prologue: 3 k-halves staged (12 ops); t0k0 forced landed ----
    stage(0, 0, 0);
    stage(0, 1, 0);
    stage(1, 0, 1);
    asm volatile("s_waitcnt vmcnt(8)" ::: "memory");
    __builtin_amdgcn_s_barrier();

#pragma unroll 1
    for (int it8 = 0; it8 < NT / 2; ++it8) {
        int s1 = 2 * it8 + 1;                       // always a real tile
        int s2 = 2 * it8 + 2; if (s2 > NT - 1) s2 = NT - 1;
        int s3 = 2 * it8 + 3; if (s3 > NT - 1) s3 = NT - 1;
        phase(0, 0, 0, s1, 1, 1, true,  false);     // ph1
        phase(0, 1, 0, 0, 0, 0, false, true);       // ph2
        phase(0, 0, 1, s2, 0, 0, true,  false);     // ph3
        phase(0, 1, 1, 0, 0, 0, false, true);       // ph4
        phase(1, 0, 0, s2, 1, 0, true,  false);     // ph5
        phase(1, 1, 0, 0, 0, 0, false, true);       // ph6
        phase(1, 0, 1, s3, 0, 1, true,  false);     // ph7
        phase(1, 1, 1, 0, 0, 0, false, true);       // ph8
    }
    asm volatile("s_waitcnt vmcnt(0)" ::: "memory");

    // ---- epilogue: dual-output C write (col<HC -> X0 else X1) ----
#pragma unroll
    for (int i = 0; i < 8; ++i) {
#pragma unroll
        for (int j = 0; j < 4; ++j) {
            int col = bn + wn * 64 + j * 16 + c16;
            bf16* dst = (col < HC) ? (X0 + col) : (X1 + col - HC);
#pragma unroll
            for (int r = 0; r < 4; ++r) {
                int row = bm + wm * 128 + i * 16 + quad * 4 + r;
                dst[(size_t)row * HC] = f2b(acc[i][j][r]);
            }
        }
    }
}

// ---------------------------------------------------------------------------
// fp32 GEMM (head MLP only)
// ---------------------------------------------------------------------------
__global__ __launch_bounds__(256) void gemm_f32(
    const float* __restrict__ A, const float* __restrict__ W,
    const float* __restrict__ bias, float* __restrict__ C,
    int M, int N, int K, float slope, int has_act)
{
    const int BK = 16;
    __shared__ float Asm[BK][64 + 1];
    __shared__ float Wsm[BK][64 + 1];
    int tid = threadIdx.x;
    int bm = blockIdx.y * 64;
    int bn = blockIdx.x * 64;
    int tr = tid >> 4;
    int tc = tid & 15;
    float acc[4][4] = {};

    for (int k0 = 0; k0 < K; k0 += BK) {
        {
            int col = tid & 15;
            int row = tid >> 4;
#pragma unroll
            for (int p = 0; p < 4; p++) {
                int r = row + p * 16;
                Asm[col][r] = A[(size_t)(bm + r) * K + k0 + col];
            }
        }
        {
            int wc = tid & 63;
            int wr = tid >> 6;
#pragma unroll
            for (int p = 0; p < 4; p++) {
                int r = wr + p * 4;
                Wsm[r][wc] = W[(size_t)(k0 + r) * N + bn + wc];
            }
        }
        __syncthreads();
#pragma unroll
        for (int kk = 0; kk < BK; kk++) {
            float a[4], w[4];
#pragma unroll
            for (int i = 0; i < 4; i++) a[i] = Asm[kk][tr * 4 + i];
#pragma unroll
            for (int j = 0; j < 4; j++) w[j] = Wsm[kk][tc * 4 + j];
#pragma unroll
            for (int i = 0; i < 4; i++)
#pragma unroll
                for (int j = 0; j < 4; j++)
                    acc[i][j] += a[i] * w[j];
        }
        __syncthreads();
    }
#pragma unroll
    for (int i = 0; i < 4; i++) {
        int r = bm + tr * 4 + i;
#pragma unroll
        for (int j = 0; j < 4; j++) {
            int cn = bn + tc * 4 + j;
            float v = acc[i][j];
            if (bias) v += bias[cn];
            if (has_act) v = (v >= 0.f) ? v : v * slope;
            C[(size_t)r * N + cn] = v;
        }
    }
}

// ---------------------------------------------------------------------------
// Batched fp32 [R,C] -> bf16 [C,R] transpose-convert (z selects tensor pair)
// ---------------------------------------------------------------------------
__global__ __launch_bounds__(256) void transpose_f2b2(
    const float* __restrict__ in0, bf16* __restrict__ out0,
    const float* __restrict__ in1, bf16* __restrict__ out1, int R, int C)
{
    const float* in = blockIdx.z ? in1 : in0;
    bf16* out = blockIdx.z ? out1 : out0;
    __shared__ float tile[32][33];
    int c0 = blockIdx.x * 32;
    int r0 = blockIdx.y * 32;
    int tx = threadIdx.x & 31;
    int ty = threadIdx.x >> 5;
#pragma unroll
    for (int k = 0; k < 4; k++) {
        int r = ty + k * 8;
        tile[r][tx] = in[(size_t)(r0 + r) * C + c0 + tx];
    }
    __syncthreads();
#pragma unroll
    for (int k = 0; k < 4; k++) {
        int rr = ty + k * 8;
        out[(size_t)(c0 + rr) * R + r0 + tx] = f2b(tile[tx][rr]);
    }
}

__global__ void f2b_vec(const float* __restrict__ in, bf16* __restrict__ out, int n)
{
    int i = blockIdx.x * 256 + threadIdx.x;
    if (i < n) out[i] = f2b(in[i]);
}

// ---------------------------------------------------------------------------
// CSR build over dst (self loops: edge ids [EE, ET) are node e-EE)
// ---------------------------------------------------------------------------
__global__ void count_deg(const int* __restrict__ ei, int* __restrict__ deg)
{
    int e = blockIdx.x * 256 + threadIdx.x;
    if (e >= ET) return;
    int d = (e < EE) ? ei[EE + e] : (e - EE);
    d = clampi(d, 0, NN - 1);
    atomicAdd(&deg[d], 1);
}

__global__ __launch_bounds__(256) void scan_deg(const int* __restrict__ deg,
                                                int* __restrict__ rs)
{
    __shared__ int part[256];
    __shared__ int psum[257];
    int tid = threadIdx.x;
    const int per = NN / 256;
    int base = tid * per;
    int s = 0;
    for (int i = 0; i < per; i++) s += deg[base + i];
    part[tid] = s;
    __syncthreads();
    if (tid == 0) {
        int acc = 0;
        for (int i = 0; i < 256; i++) { psum[i] = acc; acc += part[i]; }
        psum[256] = acc;
    }
    __syncthreads();
    int acc = psum[tid];
    for (int i = 0; i < per; i++) { rs[base + i] = acc; acc += deg[base + i]; }
    if (tid == 0) rs[NN] = psum[256];
}

__global__ void fill_csr(const int* __restrict__ ei, const int* __restrict__ rs,
                         int* __restrict__ cur, int* __restrict__ csrc)
{
    int e = blockIdx.x * 256 + threadIdx.x;
    if (e >= ET) return;
    int s, d;
    if (e < EE) { s = ei[e]; d = ei[EE + e]; } else { s = d = e - EE; }
    s = clampi(s, 0, NN - 1);
    d = clampi(d, 0, NN - 1);
    int pos = atomicAdd(&cur[d], 1);
    int slot = clampi(rs[d] + pos, 0, ET - 1);
    csrc[slot] = s;
}

// ---------------------------------------------------------------------------
// GATv2 fused wave kernel, register pipeline. Used for L4 (NH=1).
// ---------------------------------------------------------------------------
template<int NH>
__global__ __launch_bounds__(256, 4) void gat_wave6(
    const bf16* __restrict__ xl, const bf16* __restrict__ xr,
    const float* __restrict__ att, const float* __restrict__ bias,
    const int* __restrict__ rs, const int* __restrict__ csrc,
    const float* __restrict__ res, float* __restrict__ out_f,
    bf16* __restrict__ out_b, float* __restrict__ lnsums)
{
    constexpr int HC = NH * 512;
    constexpr int PF = 6;
    constexpr int NODES = (NH == 2) ? 8 : 4;
    const int tid = threadIdx.x;
    const int w = tid >> 6;
    const int lane = tid & 63;
    const int wave_id = blockIdx.x * 4 + w;

    int msrc[NODES];
    int sdeg[NODES];
#pragma unroll
    for (int it = 0; it < NODES; ++it) {
        int gw = wave_id * NODES + it;
        int n = (NH == 2) ? (gw >> 1) : gw;
        int st = rs[n];
        int deg = clampi(rs[n + 1] - st, 1, 64);
        st = clampi(st, 0, ET - 1);
        st = __builtin_amdgcn_readfirstlane(st);
        deg = __builtin_amdgcn_readfirstlane(deg);
        sdeg[it] = deg;
        msrc[it] = csrc[st + ((lane < deg) ? lane : deg - 1)];
    }

    float av0[8], av1[8];
    {
        f32x4 t0 = *(const f32x4*)(att + lane * 8);
        f32x4 t1 = *(const f32x4*)(att + lane * 8 + 4);
#pragma unroll
        for (int k = 0; k < 4; k++) { av0[k] = t0[k]; av0[4 + k] = t1[k]; }
        if (NH == 2) {
            f32x4 t2 = *(const f32x4*)(att + 512 + lane * 8);
            f32x4 t3 = *(const f32x4*)(att + 512 + lane * 8 + 4);
#pragma unroll
            for (int k = 0; k < 4; k++) { av1[k] = t2[k]; av1[4 + k] = t3[k]; }
        } else {
#pragma unroll
            for (int k = 0; k < 8; k++) av1[k] = av0[k];
        }
    }

    f32x4 rows[2][PF];
    f32x4 rpx[2];

    auto issue = [&](int it, int pb) {
        int gw = wave_id * NODES + it;
        int n = (NH == 2) ? (gw >> 1) : gw;
        int h = (NH == 2) ? (gw & 1) : 0;
        int cb = h * 512 + lane * 8;
        rpx[pb] = *(const f32x4*)(xr + (size_t)n * HC + cb);
        int dm1 = sdeg[it] - 1;
#pragma unroll
        for (int r = 0; r < PF; r++) {
            int idx = (r < dm1) ? r : dm1;
            int s = __builtin_amdgcn_readlane(msrc[it], idx);
            s = clampi(s, 0, NN - 1);
            rows[pb][r] = *(const f32x4*)(xl + (size_t)s * HC + cb);
        }
    };

    auto compute = [&](int it, int pb) {
        int gw = wave_id * NODES + it;
        int n = (NH == 2) ? (gw >> 1) : gw;
        int h = (NH == 2) ? (gw & 1) : 0;
        int cb = h * 512 + lane * 8;
        int deg = sdeg[it];

        float rv[8], av[8];
        {
            bf16x8 xb = __builtin_bit_cast(bf16x8, rpx[pb]);
#pragma unroll
            for (int k = 0; k < 8; k++) {
                rv[k] = sb2f(xb[k]);
                av[k] = h ? av1[k] : av0[k];
            }
        }

        float part[PF];
#pragma unroll
        for (int r = 0; r < PF; r++) {
            bf16x8 rb = __builtin_bit_cast(bf16x8, rows[pb][r]);
            float p0 = 0.f, p1 = 0.f, p2 = 0.f, p3 = 0.f;
#pragma unroll
            for (int k = 0; k < 8; k += 4) {
                float x0 = sb2f(rb[k + 0]);
                float x1 = sb2f(rb[k + 1]);
                float x2 = sb2f(rb[k + 2]);
                float x3 = sb2f(rb[k + 3]);
                float u0 = x0 + rv[k + 0]; u0 = (u0 >= 0.f) ? u0 : 0.2f * u0;
                float u1 = x1 + rv[k + 1]; u1 = (u1 >= 0.f) ? u1 : 0.2f * u1;
                float u2 = x2 + rv[k + 2]; u2 = (u2 >= 0.f) ? u2 : 0.2f * u2;
                float u3 = x3 + rv[k + 3]; u3 = (u3 >= 0.f) ? u3 : 0.2f * u3;
                p0 = fmaf(av[k + 0], u0, p0);
                p1 = fmaf(av[k + 1], u1, p1);
                p2 = fmaf(av[k + 2], u2, p2);
                p3 = fmaf(av[k + 3], u3, p3);
            }
            part[r] = (p0 + p1) + (p2 + p3);
        }

#pragma unroll
        for (int msk = 32; msk; msk >>= 1) {
#pragma unroll
            for (int r = 0; r < PF; r++) part[r] += __shfl_xor(part[r], msk);
        }

        float m = -1e30f;
#pragma unroll
        for (int r = 0; r < PF; r++) {
            float vr = (r < deg) ? part[r] : -1e30f;
            m = fmaxf(m, vr);
        }
        float den = 0.f;
        float pw[PF];
#pragma unroll
        for (int r = 0; r < PF; r++) {
            float e = __expf(part[r] - m);
            pw[r] = (r < deg) ? e : 0.f;
            den += pw[r];
        }

        float acc[8];
#pragma unroll
        for (int k = 0; k < 8; k++) acc[k] = 0.f;
#pragma unroll
        for (int r = 0; r < PF; r++) {
            bf16x8 rb = __builtin_bit_cast(bf16x8, rows[pb][r]);
#pragma unroll
            for (int k = 0; k < 8; k++)
                acc[k] = fmaf(pw[r], sb2f(rb[k]), acc[k]);
        }

        if (deg > PF) {
            for (int i = PF; i < deg; i++) {
                int s = __builtin_amdgcn_readlane(msrc[it], i);
                s = clampi(s, 0, NN - 1);
                f32x4 rw = *(const f32x4*)(xl + (size_t)s * HC + cb);
                bf16x8 rb = __builtin_bit_cast(bf16x8, rw);
                float pt = 0.f;
#pragma unroll
                for (int k = 0; k < 8; k++) {
                    float x = sb2f(rb[k]);
                    float u = x + rv[k];
                    u = (u >= 0.f) ? u : 0.2f * u;
                    pt = fmaf(av[k], u, pt);
                }
#pragma unroll
                for (int msk = 32; msk; msk >>= 1) pt += __shfl_xor(pt, msk);
                float mn = fmaxf(m, pt);
                float rr = __expf(m - mn);
                float pi = __expf(pt - mn);
                m = mn;
                den = den * rr + pi;
#pragma unroll
                for (int k = 0; k < 8; k++) {
                    float x = sb2f(rb[k]);
                    acc[k] = fmaf(acc[k], rr, pi * x);
                }
            }
        }

        float inv = 1.f / den;
        f32x4 b0 = *(const f32x4*)(bias + cb);
        f32x4 b1 = *(const f32x4*)(bias + cb + 4);
        float vals[8];
#pragma unroll
        for (int k = 0; k < 8; k++) {
            float bv = (k < 4) ? b0[k] : b1[k - 4];
            float v = fmaf(acc[k], inv, bv);
            v = (v >= 0.f) ? v : 0.01f * v;
            vals[k] = v;
        }
        if (res) {
            float ls = 0.f, ls2 = 0.f;
#pragma unroll
            for (int k = 0; k < 8; k++) {
                vals[k] += res[(size_t)n * HC + cb + k];
                ls += vals[k];
                ls2 += vals[k] * vals[k];
            }
#pragma unroll
            for (int v = 0; v < 2; v++) {
                f32x4 ov;
#pragma unroll
                for (int k = 0; k < 4; k++) ov[k] = vals[v * 4 + k];
                *(f32x4*)(out_f + (size_t)n * HC + cb + v * 4) = ov;
            }
            if (lnsums) {
#pragma unroll
                for (int msk = 32; msk; msk >>= 1) {
                    ls += __shfl_xor(ls, msk);
                    ls2 += __shfl_xor(ls2, msk);
                }
                if (lane == 0) {
                    int g = n >> 8;
                    atomicAdd(&lnsums[g], ls);
                    atomicAdd(&lnsums[BBG + g], ls2);
                }
            }
        } else {
            bf16x8 ov;
#pragma unroll
            for (int k = 0; k < 8; k++) ov[k] = f2bs(vals[k]);
            *(bf16x8*)(out_b + (size_t)n * HC + cb) = ov;
        }
    };

    issue(0, 0);
#pragma unroll
    for (int it = 0; it < NODES; ++it) {
        int pb = it & 1;
        if (it + 1 < NODES) issue(it + 1, pb ^ 1);
        compute(it, pb);
    }
}

// ---------------------------------------------------------------------------
// GATv2 edge phase, LDS-staged async pipeline with counted vmcnt (NH=2).
// ---------------------------------------------------------------------------
template<int NH>
__global__ __launch_bounds__(256) void gat_wave7(
    const bf16* __restrict__ xl, const bf16* __restrict__ xr,
    const float* __restrict__ att, const float* __restrict__ bias,
    const int* __restrict__ rs, const int* __restrict__ csrc,
    const float* __restrict__ res, float* __restrict__ out_f,
    bf16* __restrict__ out_b, float* __restrict__ lnsums)
{
    constexpr int HC = NH * 512;
    constexpr int PF = 6;
    constexpr int NODES = (NH == 2) ? 8 : 4;
    constexpr int WPB = 4;
    constexpr int SLOTS = 7;
    __shared__ char smem[WPB * 2 * SLOTS * 1024];

    const int tid = threadIdx.x;
    const int w = tid >> 6;
    const int lane = tid & 63;
    const int wave_id = blockIdx.x * WPB + w;

    int msrc[NODES];
    int sdeg[NODES];
#pragma unroll
    for (int it = 0; it < NODES; ++it) {
        int gw = wave_id * NODES + it;
        int n = (NH == 2) ? (gw >> 1) : gw;
        int st = rs[n];
        int deg = clampi(rs[n + 1] - st, 1, 64);
        st = clampi(st, 0, ET - 1);
        st = __builtin_amdgcn_readfirstlane(st);
        deg = __builtin_amdgcn_readfirstlane(deg);
        sdeg[it] = deg;
        msrc[it] = csrc[st + ((lane < deg) ? lane : deg - 1)];
    }

    float av0[8], av1[8], bv0[8], bv1[8];
    {
        f32x4 t0 = *(const f32x4*)(att + lane * 8);
        f32x4 t1 = *(const f32x4*)(att + lane * 8 + 4);
        f32x4 u0 = *(const f32x4*)(bias + lane * 8);
        f32x4 u1 = *(const f32x4*)(bias + lane * 8 + 4);
#pragma unroll
        for (int k = 0; k < 4; k++) {
            av0[k] = t0[k]; av0[4 + k] = t1[k];
            bv0[k] = u0[k]; bv0[4 + k] = u1[k];
        }
        if (NH == 2) {
            f32x4 t2 = *(const f32x4*)(att + 512 + lane * 8);
            f32x4 t3 = *(const f32x4*)(att + 512 + lane * 8 + 4);
            f32x4 u2 = *(const f32x4*)(bias + 512 + lane * 8);
            f32x4 u3 = *(const f32x4*)(bias + 512 + lane * 8 + 4);
#pragma unroll
            for (int k = 0; k < 4; k++) {
                av1[k] = t2[k]; av1[4 + k] = t3[k];
                bv1[k] = u2[k]; bv1[4 + k] = u3[k];
            }
        } else {
#pragma unroll
            for (int k = 0; k < 8; k++) { av1[k] = av0[k]; bv1[k] = bv0[k]; }
        }
    }

    auto issue = [&](int it, int pb) {
        int gw = wave_id * NODES + it;
        int n = (NH == 2) ? (gw >> 1) : gw;
        int h = (NH == 2) ? (gw & 1) : 0;
        char* buf = smem + (size_t)((w * 2 + pb) * SLOTS) * 1024;
        const bf16* xrrow = xr + (size_t)n * HC + h * 512 + lane * 8;
        __builtin_amdgcn_global_load_lds((const AS1 void*)xrrow,
            (AS3 void*)buf, 16, 0, 0);
        int dm1 = sdeg[it] - 1;
#pragma unroll
        for (int r = 0; r < PF; r++) {
            int idx = (r < dm1) ? r : dm1;
            int s = __builtin_amdgcn_readlane(msrc[it], idx);
            s = clampi(s, 0, NN - 1);
            const bf16* row = xl + (size_t)s * HC + h * 512 + lane * 8;
            __builtin_amdgcn_global_load_lds((const AS1 void*)row,
                (AS3 void*)(buf + (1 + r) * 1024), 16, 0, 0);
        }
    };

    auto compute = [&](int it, int pb) {
        int gw = wave_id * NODES + it;
        int n = (NH == 2) ? (gw >> 1) : gw;
        int h = (NH == 2) ? (gw & 1) : 0;
        int cb = h * 512 + lane * 8;
        int deg = sdeg[it];
        char* buf = smem + (size_t)((w * 2 + pb) * SLOTS) * 1024;

        float rv[8], av[8];
        {
            bf16x8 xb = *(const bf16x8*)(buf + lane * 16);
#pragma unroll
            for (int k = 0; k < 8; k++) {
                rv[k] = sb2f(xb[k]);
                av[k] = h ? av1[k] : av0[k];
            }
        }
        bf16x8 rloc[PF];
#pragma unroll
        for (int r = 0; r < PF; r++)
            rloc[r] = *(const bf16x8*)(buf + (1 + r) * 1024 + lane * 16);

        float part[PF];
#pragma unroll
        for (int r = 0; r < PF; r++) {
            float p0 = 0.f, p1 = 0.f, p2 = 0.f, p3 = 0.f;
#pragma unroll
            for (int k = 0; k < 8; k += 4) {
                float x0 = sb2f(rloc[r][k + 0]);
                float x1 = sb2f(rloc[r][k + 1]);
                float x2 = sb2f(rloc[r][k + 2]);
                float x3 = sb2f(rloc[r][k + 3]);
                float u0 = x0 + rv[k + 0]; u0 = (u0 >= 0.f) ? u0 : 0.2f * u0;
                float u1 = x1 + rv[k + 1]; u1 = (u1 >= 0.f) ? u1 : 0.2f * u1;
                float u2 = x2 + rv[k + 2]; u2 = (u2 >= 0.f) ? u2 : 0.2f * u2;
                float u3 = x3 + rv[k + 3]; u3 = (u3 >= 0.f) ? u3 : 0.2f * u3;
                p0 = fmaf(av[k + 0], u0, p0);
                p1 = fmaf(av[k + 1], u1, p1);
                p2 = fmaf(av[k + 2], u2, p2);
                p3 = fmaf(av[k + 3], u3, p3);
            }
            part[r] = (p0 + p1) + (p2 + p3);
        }

#pragma unroll
        for (int msk = 32; msk; msk >>= 1) {
#pragma unroll
            for (int r = 0; r < PF; r++) part[r] += __shfl_xor(part[r], msk);
        }

        float m = -1e30f;
#pragma unroll
        for (int r = 0; r < PF; r++) {
            float vr = (r < deg) ? part[r] : -1e30f;
            m = fmaxf(m, vr);
        }
        float den = 0.f;
        float pw[PF];
#pragma unroll
        for (int r = 0; r < PF; r++) {
            float e = __expf(part[r] - m);
            pw[r] = (r < deg) ? e : 0.f;
            den += pw[r];
        }

        float acc[8];
#pragma unroll
        for (int k = 0; k < 8; k++) acc[k] = 0.f;
#pragma unroll
        for (int r = 0; r < PF; r++) {
#pragma unroll
            for (int k = 0; k < 8; k++)
                acc[k] = fmaf(pw[r], sb2f(rloc[r][k]), acc[k]);
        }

        if (deg > PF) {
            for (int i = PF; i < deg; i++) {
                int s = __builtin_amdgcn_readlane(msrc[it], i);
                s = clampi(s, 0, NN - 1);
                f32x4 rw = *(const f32x4*)(xl + (size_t)s * HC + cb);
                bf16x8 rb = __builtin_bit_cast(bf16x8, rw);
                float pt = 0.f;
#pragma unroll
                for (int k = 0; k < 8; k++) {
                    float x = sb2f(rb[k]);
                    float u = x + rv[k];
                    u = (u >= 0.f) ? u : 0.2f * u;
                    pt = fmaf(av[k], u, pt);
                }
#pragma unroll
                for (int msk = 32; msk; msk >>= 1) pt += __shfl_xor(pt, msk);
                float mn = fmaxf(m, pt);
                float rr = __expf(m - mn);
                float pi = __expf(pt - mn);
                m = mn;
                den = den * rr + pi;
#pragma unroll
                for (int k = 0; k < 8; k++) {
                    float x = sb2f(rb[k]);
                    acc[k] = fmaf(acc[k], rr, pi * x);
                }
            }
        }

        float inv = 1.f / den;
        float vals[8];
#pragma unroll
        for (int k = 0; k < 8; k++) {
            float bv = h ? bv1[k] : bv0[k];
            float v = fmaf(acc[k], inv, bv);
            v = (v >= 0.f) ? v : 0.01f * v;
            vals[k] = v;
        }
        bf16x8 ov;
#pragma unroll
        for (int k = 0; k < 8; k++) ov[k] = f2bs(vals[k]);
        *(bf16x8*)(out_b + (size_t)n * HC + cb) = ov;
    };

    issue(0, 0);
#pragma unroll
    for (int it = 0; it < NODES; ++it) {
        int pb = it & 1;
        if (it + 1 < NODES) {
            issue(it + 1, pb ^ 1);
            asm volatile("s_waitcnt vmcnt(7)" ::: "memory");
        } else {
            asm volatile("s_waitcnt vmcnt(0)" ::: "memory");
        }
        __builtin_amdgcn_sched_barrier(0);
        compute(it, pb);
    }
}

// ---------------------------------------------------------------------------
// LN apply + channel-wise online-softmax aggregation, node-chunked partials.
// ---------------------------------------------------------------------------
__global__ __launch_bounds__(256) void aggr_partial(
    const float* __restrict__ h, const float* __restrict__ lnsums,
    const float* __restrict__ lnw, const float* __restrict__ lnb,
    const float* __restrict__ t_, float* __restrict__ pm,
    float* __restrict__ pd, float* __restrict__ pa)
{
    int g = blockIdx.x, ch = blockIdx.y, nk = blockIdx.z;
    int tid = threadIdx.x;
    int c = ch * 256 + tid;
    const float tot = (float)(NG * DD);
    float S = lnsums[g], S2 = lnsums[BBG + g];
    float mu = S / tot;
    float iv = rsqrtf(fmaxf(S2 / tot - mu * mu, 0.f) + 1e-5f);
    float w = lnw[c], b = lnb[c], t = t_[0];
    size_t base = (size_t)g * NG * DD + (size_t)nk * 32 * DD + c;
    float m = -1e30f, den = 0.f, acc = 0.f;
    for (int i = 0; i < 32; i++) {
        float hn = (h[base + (size_t)i * DD] - mu) * iv * w + b;
        float lg = hn * t;
        if (lg > m) {
            float r = __expf(m - lg);
            den *= r; acc *= r; m = lg;
        }
        float p = __expf(lg - m);
        den += p; acc += p * hn;
    }
    size_t idx = (((size_t)g * 2 + ch) * 8 + nk) * 256 + tid;
    pm[idx] = m; pd[idx] = den; pa[idx] = acc;
}

__global__ __launch_bounds__(256) void aggr_combine(
    const float* __restrict__ pm, const float* __restrict__ pd,
    const float* __restrict__ pa, float* __restrict__ gout)
{
    int g = blockIdx.x, ch = blockIdx.y;
    int tid = threadIdx.x;
    size_t base = (((size_t)g * 2 + ch) * 8) * 256 + tid;
    float m = -1e30f;
#pragma unroll
    for (int k = 0; k < 8; k++) m = fmaxf(m, pm[base + k * 256]);
    float den = 0.f, acc = 0.f;
#pragma unroll
    for (int k = 0; k < 8; k++) {
        float r = __expf(pm[base + k * 256] - m);
        den += pd[base + k * 256] * r;
        acc += pa[base + k * 256] * r;
    }
    gout[(size_t)g * DD + ch * 256 + tid] = acc / den;
}

// ---------------------------------------------------------------------------
extern "C" void kernel_launch(void* const* d_in, const int* in_sizes, int n_in,
                              void* d_out, int out_size, void* d_ws, size_t ws_size,
                              hipStream_t stream)
{
    const float* x      = (const float*)d_in[0];
    const int*   ei     = (const int*)d_in[1];
    const float* xt_w1  = (const float*)d_in[3];
    const float* xt_b1  = (const float*)d_in[4];
    const float* xt_w2  = (const float*)d_in[5];
    const float* xt_b2  = (const float*)d_in[6];
    const float* ln_w   = (const float*)d_in[27];
    const float* ln_b   = (const float*)d_in[28];
    const float* aggr_t = (const float*)d_in[29];
    const float* m_w1   = (const float*)d_in[30];
    const float* m_b1   = (const float*)d_in[31];
    const float* m_w2   = (const float*)d_in[32];
    const float* m_b2   = (const float*)d_in[33];
    const float* m_w3   = (const float*)d_in[34];
    const float* m_b3   = (const float*)d_in[35];
    float* out = (float*)d_out;

    // ---- workspace layout (256B aligned); ints first ----
    char* p = (char*)d_ws;
    auto take = [&](size_t bytes) {
        char* r = p;
        p += (bytes + 255) & ~(size_t)255;
        return r;
    };
    int* i_deg     = (int*)take((size_t)(NN + 1) * 4);
    int* i_rs      = (int*)take((size_t)(NN + 1) * 4);
    int* i_cur     = (int*)take((size_t)NN * 4);
    int* i_src     = (int*)take((size_t)ET * 4);
    float* f_sums  = (float*)take((size_t)2 * BBG * 4);
    float* f_pm    = (float*)take((size_t)BBG * 2 * 8 * 256 * 4);
    float* f_pd    = (float*)take((size_t)BBG * 2 * 8 * 256 * 4);
    float* f_pa    = (float*)take((size_t)BBG * 2 * 8 * 256 * 4);
    float* b_g     = (float*)take((size_t)BBG * DD * 4);
    float* b_m1    = (float*)take((size_t)BBG * 384 * 4);
    float* b_m2    = (float*)take((size_t)BBG * 256 * 4);
    float* b_res   = (float*)take((size_t)NN * DD * 4);
    float* b_h     = (float*)take((size_t)NN * DD * 4);
    bf16* b_resb   = (bf16*)take((size_t)NN * DD * 2);
    bf16* b_hb     = (bf16*)take((size_t)NN * 1024 * 2);
    bf16* b_xlb    = (bf16*)take((size_t)NN * 1024 * 2);
    bf16* b_xrb    = (bf16*)take((size_t)NN * 1024 * 2);
    bf16* b_xb     = (bf16*)take((size_t)2 * NN * 32 * 2);
    bf16* b_wcat   = (bf16*)take((size_t)2048 * 1024 * 2);  // [wlT; wrT]
    bf16* b_w1b    = (bf16*)take((size_t)32 * 256 * 2);
    bf16* b_w2b    = (bf16*)take((size_t)256 * 256 * 2);
    bf16* b_t1b = b_hb;

    dim3 blk(256);

    // ---- CSR build + LN-sum zero ----
    hipMemsetAsync(i_deg, 0, (size_t)(NN + 1) * 4, stream);
    hipMemsetAsync(i_cur, 0, (size_t)NN * 4, stream);
    hipMemsetAsync(f_sums, 0, (size_t)2 * BBG * 4, stream);
    count_deg<<<ET / 256, blk, 0, stream>>>(ei, i_deg);
    scan_deg<<<1, blk, 0, stream>>>(i_deg, i_rs);
    fill_csr<<<ET / 256, blk, 0, stream>>>(ei, i_rs, i_cur, i_src);

    // ---- weight converts for x_trans + x convert ----
    f2b_vec<<<(2 * NN * 32 + 255) / 256, blk, 0, stream>>>(x, b_xb, 2 * NN * 32);
    transpose_f2b2<<<dim3(256 / 32, 32 / 32, 1), blk, 0, stream>>>(
        xt_w1, b_w1b, xt_w1, b_w1b, 32, 256);
    transpose_f2b2<<<dim3(256 / 32, 256 / 32, 1), blk, 0, stream>>>(
        xt_w2, b_w2b, xt_w2, b_w2b, 256, 256);

    // ---- x_trans ----
    gemm_mfma_bt<<<dim3(256 / 128, 32768 / 128), blk, 0, stream>>>(
        b_xb, b_w1b, xt_b1, (float*)nullptr, b_t1b, 32768, 256, 32, 0.01f, 1);
    gemm_mfma_bt<<<dim3(256 / 128, 32768 / 128), blk, 0, stream>>>(
        b_t1b, b_w2b, xt_b2, b_res, b_resb, 32768, 256, 256, 0.f, 0);

    // ---- 5 GATv2 layers ----
    for (int L = 0; L < 5; L++) {
        const float* wl  = (const float*)d_in[7 + 4 * L];
        const float* wr  = (const float*)d_in[8 + 4 * L];
        const float* att = (const float*)d_in[9 + 4 * L];
        const float* gb  = (const float*)d_in[10 + 4 * L];
        int Fin = (L == 0) ? 512 : 1024;
        int HC  = (L == 4) ? 512 : 1024;
        const bf16* hin = (L == 0) ? b_resb : b_hb;

        transpose_f2b2<<<dim3(HC / 32, Fin / 32, 2), blk, 0, stream>>>(
            wl, b_wcat, wr, b_wcat + (size_t)HC * Fin, Fin, HC);
        if (L == 0)
            gemm256_8ph<512><<<dim3(2048 / 256, NN / 256), dim3(512), 0, stream>>>(
                hin, b_wcat, b_xlb, b_xrb, 1024);
        else if (L == 4)
            gemm256_8ph<1024><<<dim3(1024 / 256, NN / 256), dim3(512), 0, stream>>>(
                hin, b_wcat, b_xlb, b_xrb, 512);
        else
            gemm256_8ph<1024><<<dim3(2048 / 256, NN / 256), dim3(512), 0, stream>>>(
                hin, b_wcat, b_xlb, b_xrb, 1024);

        if (L == 4) {
            gat_wave6<1><<<1024, blk, 0, stream>>>(
                b_xlb, b_xrb, att, gb, i_rs, i_src,
                b_res, b_h, (bf16*)nullptr, f_sums);
        } else {
            gat_wave7<2><<<1024, blk, 0, stream>>>(
                b_xlb, b_xrb, att, gb, i_rs, i_src,
                (const float*)nullptr, (float*)nullptr, b_hb, (float*)nullptr);
        }
    }

    // ---- graph LN + softmax aggregation (single pass + combine) ----
    aggr_partial<<<dim3(BBG, 2, 8), blk, 0, stream>>>(
        b_h, f_sums, ln_w, ln_b, aggr_t, f_pm, f_pd, f_pa);
    aggr_combine<<<dim3(BBG, 2), blk, 0, stream>>>(f_pm, f_pd, f_pa, b_g);

    // ---- head MLP 512 -> 384 -> 256 -> 128 (fp32) ----
    gemm_f32<<<dim3(384 / 64, 1), blk, 0, stream>>>(
        b_g, m_w1, m_b1, b_m1, 64, 384, 512, 0.01f, 1);
    gemm_f32<<<dim3(256 / 64, 1), blk, 0, stream>>>(
        b_m1, m_w2, m_b2, b_m2, 64, 256, 384, 0.01f, 1);
    gemm_f32<<<dim3(128 / 64, 1), blk, 0, stream>>>(
        b_m2, m_w3, m_b3, out, 64, 128, 256, 0.f, 0);
}